// Round 13
// baseline (267.473 us; speedup 1.0000x reference)
//
#include <hip/hip_runtime.h>
#include <hip/hip_bf16.h>
#include <cstdint>

#define S_LEN 2048
#define D_MOD 1024
#define N_HEADS 16
#define DK 64
#define D_FF 4096

typedef __bf16 bf16x8 __attribute__((ext_vector_type(8)));
typedef float f32x4 __attribute__((ext_vector_type(4)));

#define MFMA16(a, b, c) __builtin_amdgcn_mfma_f32_16x16x32_bf16((a), (b), (c), 0, 0, 0)

__device__ inline unsigned pack_bf16x2(float a, float b)
{
    unsigned short ua = __builtin_bit_cast(unsigned short, (__bf16)a);
    unsigned short ub = __builtin_bit_cast(unsigned short, (__bf16)b);
    return (unsigned)ua | ((unsigned)ub << 16);
}

// async global->LDS, 16B per lane; LDS dest must equal waveBase + lane*16
__device__ inline void gload16(const void* g, void* l)
{
    __builtin_amdgcn_global_load_lds(
        (const __attribute__((address_space(1))) unsigned int*)g,
        (__attribute__((address_space(3))) unsigned int*)l, 16, 0, 0);
}

// ---------------------------------------------------------------------------
// Shared GEMM block body, 2-phase double-buffered with counted vmcnt (T3-min).
// As: 2*128*8 uint4, Bs: 2*BN*8 uint4.
// ---------------------------------------------------------------------------
template<int BN, bool RELU, bool RES, bool RES2, bool WF32, bool WBF16, bool WVT>
__device__ __forceinline__
void gemm_dev(const __bf16* __restrict__ A, const __bf16* __restrict__ BT,
              const float* __restrict__ bias, const float* __restrict__ res,
              const float* __restrict__ res2,
              float* __restrict__ Cf, __bf16* __restrict__ Cb,
              __bf16* __restrict__ vt,
              int N, int Kst, int Klp, int bx, int by,
              uint4* As, uint4* Bs)
{
    constexpr int NFRAG = BN / 32;
    const int tid = threadIdx.x;
    const int lane = tid & 63;
    const int w = tid >> 6;
    const int lrow = lane & 15;
    const int g = lane >> 4;
    const int bm = by * 128;
    const int bn = bx * BN;
    const int wrow = (w >> 1) * 64;
    const int wcol = (w & 1) * (BN / 2);

    f32x4 acc[4][NFRAG];
    for (int m = 0; m < 4; m++)
        for (int n = 0; n < NFRAG; n++)
            acc[m][n] = (f32x4){0.f, 0.f, 0.f, 0.f};

    const int srow = tid >> 3;
    const int sc = tid & 7;
    const __bf16* Ag = A + (size_t)(bm + srow) * Kst + sc * 8;
    const __bf16* Bg = BT + (size_t)(bn + srow) * Kst + sc * 8;

    auto stage = [&](int kt, int tb) {
        uint4* Ad = As + tb * 128 * 8;
        uint4* Bd = Bs + tb * BN * 8;
        #pragma unroll
        for (int p = 0; p < 4; p++)
            gload16(Ag + (size_t)(p * 32) * Kst + kt, &Ad[(srow + p * 32) * 8 + sc]);
        #pragma unroll
        for (int p = 0; p < NFRAG; p++)
            gload16(Bg + (size_t)(p * 32) * Kst + kt, &Bd[(srow + p * 32) * 8 + sc]);
    };

    stage(0, 0);

    int it = 0;
    for (int kt = 0; kt < Klp; kt += 64, ++it) {
        const int cur = it & 1;
        if (kt + 64 < Klp) {
            stage(kt + 64, cur ^ 1);
            // wait for CURRENT tile only; next tile's (4+NFRAG) loads stay in flight
            if constexpr (NFRAG == 4)
                asm volatile("s_waitcnt vmcnt(8)" ::: "memory");
            else
                asm volatile("s_waitcnt vmcnt(6)" ::: "memory");
        } else {
            asm volatile("s_waitcnt vmcnt(0)" ::: "memory");
        }
        __syncthreads();
        const uint4* Ab = As + cur * 128 * 8;
        const uint4* Bb = Bs + cur * BN * 8;
        #pragma unroll
        for (int kk = 0; kk < 2; kk++) {
            bf16x8 af[4], bfr[NFRAG];
            int c = kk * 4 + g;
            #pragma unroll
            for (int m = 0; m < 4; m++)
                af[m] = __builtin_bit_cast(bf16x8, Ab[(wrow + m * 16 + lrow) * 8 + c]);
            #pragma unroll
            for (int n = 0; n < NFRAG; n++)
                bfr[n] = __builtin_bit_cast(bf16x8, Bb[(wcol + n * 16 + lrow) * 8 + c]);
            #pragma unroll
            for (int m = 0; m < 4; m++)
                #pragma unroll
                for (int n = 0; n < NFRAG; n++)
                    acc[m][n] = MFMA16(af[m], bfr[n], acc[m][n]);
        }
        __syncthreads();   // cur reads done; next iter restages into cur
    }

    for (int n = 0; n < NFRAG; n++) {
        int col = bn + wcol + n * 16 + lrow;
        float bval = bias ? bias[col] : 0.f;
        for (int m = 0; m < 4; m++) {
            int row0 = bm + wrow + m * 16 + g * 4;
            float vv[4];
            for (int r = 0; r < 4; r++) {
                int row = row0 + r;
                float v = acc[m][n][r] + bval;
                if (RELU) v = fmaxf(v, 0.f);
                if (RES) v += res[(size_t)row * N + col];
                if (RES2) v += res2[(size_t)row * N + col];
                vv[r] = v;
                if (WF32) Cf[(size_t)row * N + col] = v;
                if (WBF16) Cb[(size_t)row * N + col] = (__bf16)v;
            }
            if (WVT && col >= 2048) {
                uint2 pk;
                pk.x = pack_bf16x2(vv[0], vv[1]);
                pk.y = pack_bf16x2(vv[2], vv[3]);
                *(uint2*)(vt + (size_t)(col - 2048) * S_LEN + row0) = pk;
            }
        }
    }
}

// ---------------------------------------------------------------------------
// LayerNorm row body (4-input fused variant: v = a + b + c + bias[col])
// ---------------------------------------------------------------------------
__device__ __forceinline__
void ln_row_v(int row, float4 v, const float* __restrict__ gamma,
              const float* __restrict__ beta, __bf16* __restrict__ outb,
              float* __restrict__ outf, float* red)
{
    int tid = threadIdx.x;
    float s = v.x + v.y + v.z + v.w;
    float sq = v.x * v.x + v.y * v.y + v.z * v.z + v.w * v.w;
    for (int off = 32; off; off >>= 1) {
        s += __shfl_down(s, off);
        sq += __shfl_down(sq, off);
    }
    int wid = tid >> 6;
    if ((tid & 63) == 0) { red[wid] = s; red[wid + 4] = sq; }
    __syncthreads();
    s = red[0] + red[1] + red[2] + red[3];
    sq = red[4] + red[5] + red[6] + red[7];
    float mean = s * (1.f / D_MOD);
    float var = fmaxf(sq * (1.f / D_MOD) - mean * mean, 0.f);
    float inv = 1.f / (sqrtf(var) + 1e-6f);
    float4 gv = ((const float4*)gamma)[tid];
    float4 bv = ((const float4*)beta)[tid];
    float y0 = gv.x * ((v.x - mean) * inv) + bv.x;
    float y1 = gv.y * ((v.y - mean) * inv) + bv.y;
    float y2 = gv.z * ((v.z - mean) * inv) + bv.z;
    float y3 = gv.w * ((v.w - mean) * inv) + bv.w;
    uint2 pk;
    pk.x = pack_bf16x2(y0, y1);
    pk.y = pack_bf16x2(y2, y3);
    ((uint2*)(outb + (size_t)row * D_MOD))[tid] = pk;
    if (outf) {
        float4 o = {y0, y1, y2, y3};
        ((float4*)(outf + (size_t)row * D_MOD))[tid] = o;
    }
}

__device__ __forceinline__
void ln_row(int row, const float* __restrict__ x, const float* __restrict__ gamma,
            const float* __restrict__ beta, __bf16* __restrict__ outb,
            float* __restrict__ outf, float* red)
{
    float4 v = ((const float4*)(x + (size_t)row * D_MOD))[threadIdx.x];
    ln_row_v(row, v, gamma, beta, outb, outf, red);
}

// ---------------------------------------------------------------------------
// P tile write body (kt <= qt)
// ---------------------------------------------------------------------------
__device__ __forceinline__
void pwrite_tile(const __bf16* __restrict__ qkv, const float* __restrict__ Obuf,
                 float* __restrict__ P, int h, int qt, int kt)
{
    const int tid = threadIdx.x;
    const int lane = tid & 63;
    const int w = tid >> 6;
    const int lrow = lane & 15;
    const int g = lane >> 4;
    const float c1 = 0.18033688f;
    const __bf16* ksec = qkv + 1024;
    const size_t Pb = (size_t)h * S_LEN * S_LEN;

    bf16x8 qfr[2][2];
    #pragma unroll
    for (int qq = 0; qq < 2; qq++)
        #pragma unroll
        for (int kk = 0; kk < 2; kk++)
            qfr[qq][kk] = *(const bf16x8*)(qkv +
                (size_t)(qt * 128 + w * 32 + qq * 16 + lrow) * 3072 + h * DK + kk * 32 + g * 8);

    f32x4 acc[2][8];
    #pragma unroll
    for (int qq = 0; qq < 2; qq++)
        #pragma unroll
        for (int mf = 0; mf < 8; mf++) acc[qq][mf] = (f32x4){0.f, 0.f, 0.f, 0.f};
    #pragma unroll
    for (int kk = 0; kk < 2; kk++) {
        #pragma unroll
        for (int mf = 0; mf < 8; mf++) {
            bf16x8 kf = *(const bf16x8*)(ksec +
                (size_t)(kt * 128 + mf * 16 + lrow) * 3072 + h * DK + kk * 32 + g * 8);
            acc[0][mf] = MFMA16(kf, qfr[0][kk], acc[0][mf]);
            acc[1][mf] = MFMA16(kf, qfr[1][kk], acc[1][mf]);
        }
    }

    #pragma unroll
    for (int qq = 0; qq < 2; qq++) {
        int q = qt * 128 + w * 32 + qq * 16 + lrow;
        float offv = Obuf[h * S_LEN + q];
        float* prow = P + Pb + (size_t)q * S_LEN;
        if (kt == qt) {
            #pragma unroll
            for (int mf = 0; mf < 8; mf++) {
                int kvb = kt * 128 + mf * 16 + g * 4;
                f32x4 st;
                st[0] = (kvb + 0 <= q) ? exp2f(acc[qq][mf][0] * c1 + offv) : 0.f;
                st[1] = (kvb + 1 <= q) ? exp2f(acc[qq][mf][1] * c1 + offv) : 0.f;
                st[2] = (kvb + 2 <= q) ? exp2f(acc[qq][mf][2] * c1 + offv) : 0.f;
                st[3] = (kvb + 3 <= q) ? exp2f(acc[qq][mf][3] * c1 + offv) : 0.f;
                __builtin_nontemporal_store(st, (f32x4*)(prow + kvb));
            }
        } else {
            #pragma unroll
            for (int mf = 0; mf < 8; mf++) {
                int kvb = kt * 128 + mf * 16 + g * 4;
                f32x4 st;
                st[0] = exp2f(acc[qq][mf][0] * c1 + offv);
                st[1] = exp2f(acc[qq][mf][1] * c1 + offv);
                st[2] = exp2f(acc[qq][mf][2] * c1 + offv);
                st[3] = exp2f(acc[qq][mf][3] * c1 + offv);
                __builtin_nontemporal_store(st, (f32x4*)(prow + kvb));
            }
        }
    }
}

// zero-fill one strict-upper-triangle 128x128 P tile, zid in [0,1920)
__device__ __forceinline__
void zfill_tile(float* __restrict__ P, int zid)
{
    int tid = threadIdx.x;
    int h = zid / 120;
    int pr = zid - h * 120;
    int qt = 0, acc = 0;
    while (pr >= acc + 15 - qt) { acc += 15 - qt; qt++; }
    int kt = qt + 1 + (pr - acc);
    f32x4 z = {0.f, 0.f, 0.f, 0.f};
    float* base = P + (size_t)h * S_LEN * S_LEN + (size_t)(qt * 128) * S_LEN + kt * 128;
    #pragma unroll
    for (int i = 0; i < 16; i++) {
        int idx = i * 256 + tid;
        int row = idx >> 5, c = idx & 31;
        __builtin_nontemporal_store(z, (f32x4*)(base + (size_t)row * S_LEN + c * 4));
    }
}

// ---------------------------------------------------------------------------
// prep1: [0,12288) weight transposes; [12288,14336) converts; [14336,14464)
// bias_stage1 partials.
// ---------------------------------------------------------------------------
__global__ __launch_bounds__(256)
void prep1(const float* __restrict__ Wq, const float* __restrict__ Wk,
           const float* __restrict__ Wv, const float* __restrict__ W2,
           const float* __restrict__ Wf1, const float* __restrict__ Wf2,
           const float* __restrict__ W_in, const float* __restrict__ Wo,
           const float* __restrict__ b_in, const float* __restrict__ bo,
           __bf16* __restrict__ WqkvT, __bf16* __restrict__ W2T,
           __bf16* __restrict__ Wf1T, __bf16* __restrict__ Wf2T,
           __bf16* __restrict__ Win_b, __bf16* __restrict__ Wo_b,
           float* __restrict__ part)
{
    __shared__ float tile[32][33];
    int id = blockIdx.x;
    int tid = threadIdx.x;
    if (id < 12288) {
        const float* W; __bf16* WT; int K, N, n0, k0;
        if (id < 4096) {
            int m = id >> 10; id &= 1023;
            K = 1024; N = 1024;
            n0 = (id & 31) * 32; k0 = (id >> 5) * 32;
            W = m == 0 ? Wq : (m == 1 ? Wk : (m == 2 ? Wv : W2));
            WT = m == 3 ? W2T : WqkvT + (size_t)m * 1024 * 1024;
        } else if (id < 8192) {
            id -= 4096;
            K = 1024; N = 4096;
            n0 = (id & 127) * 32; k0 = (id >> 7) * 32;
            W = Wf1; WT = Wf1T;
        } else {
            id -= 8192;
            K = 4096; N = 1024;
            n0 = (id & 31) * 32; k0 = (id >> 5) * 32;
            W = Wf2; WT = Wf2T;
        }
        int tx = tid & 31, ty = tid >> 5;
        for (int i = 0; i < 4; i++)
            tile[ty + i * 8][tx] = W[(size_t)(k0 + ty + i * 8) * N + n0 + tx];
        __syncthreads();
        for (int i = 0; i < 4; i++)
            WT[(size_t)(n0 + ty + i * 8) * K + k0 + tx] = (__bf16)tile[tx][ty + i * 8];
        return;
    }
    id -= 12288;
    if (id < 2048) {
        const float* W = id < 1024 ? W_in : Wo;
        __bf16* o = id < 1024 ? Win_b : Wo_b;
        int i = (id & 1023) * 256 + tid;
        float4 v = ((const float4*)W)[i];
        uint2 pk;
        pk.x = pack_bf16x2(v.x, v.y);
        pk.y = pack_bf16x2(v.z, v.w);
        ((uint2*)o)[i] = pk;
        return;
    }
    id -= 2048;
    {
        int n = (id & 15) * 256 + tid;
        int kc = id >> 4;
        int sel = n >> 10, col = n & 1023;
        const float* W = sel == 0 ? Wq : (sel == 1 ? Wk : (sel == 2 ? Wv : W2));
        const float* src = sel < 3 ? b_in : bo;
        float s = 0.f;
        for (int k = kc * 128; k < kc * 128 + 128; k++)
            s += src[k] * W[(size_t)k * 1024 + col];
        part[kc * 4096 + n] = s;
    }
}

// ---------------------------------------------------------------------------
// prep2: [0,384) WqkvCT gemm; [384,512) WcombT gemm; [512,528) bias_stage2;
// [528,2576) LN1 rows.
// ---------------------------------------------------------------------------
__global__ __launch_bounds__(256, 2)
void prep2(const __bf16* __restrict__ WqkvT, const __bf16* __restrict__ Win_b,
           __bf16* __restrict__ WqkvCT,
           const __bf16* __restrict__ W2T, const __bf16* __restrict__ Wo_b,
           __bf16* __restrict__ WcombT,
           const float* __restrict__ part,
           const float* __restrict__ bq, const float* __restrict__ bk,
           const float* __restrict__ bv, const float* __restrict__ b2,
           float* __restrict__ bqkv, float* __restrict__ bcomb,
           const float* __restrict__ x, const float* __restrict__ g1,
           const float* __restrict__ beta1, __bf16* __restrict__ xn_b)
{
    __shared__ uint4 As[2 * 128 * 8];
    __shared__ uint4 Bs[2 * 64 * 8];
    int id = blockIdx.x;
    int tid = threadIdx.x;
    if (id < 384) {
        gemm_dev<64, false, false, false, false, true, false>(
            WqkvT, Win_b, nullptr, nullptr, nullptr, nullptr, WqkvCT, nullptr,
            1024, 1024, 1024, id & 15, id >> 4, As, Bs);
        return;
    }
    id -= 384;
    if (id < 128) {
        gemm_dev<64, false, false, false, false, true, false>(
            W2T, Wo_b, nullptr, nullptr, nullptr, nullptr, WcombT, nullptr,
            1024, 1024, 1024, id & 15, id >> 4, As, Bs);
        return;
    }
    id -= 128;
    if (id < 16) {
        int n = id * 256 + tid;
        int sel = n >> 10, col = n & 1023;
        float s = sel == 0 ? bq[col] : (sel == 1 ? bk[col] : (sel == 2 ? bv[col] : b2[col]));
        for (int kc = 0; kc < 8; kc++) s += part[kc * 4096 + n];
        if (n < 3072) bqkv[n] = s; else bcomb[col] = s;
        return;
    }
    id -= 16;
    ln_row(id, x, g1, beta1, xn_b, nullptr, (float*)As);
}

// ---------------------------------------------------------------------------
// qkv_zf: [0,384) qkv GEMM (with fused VT epilogue); [384,1344) P zero-fill
// ---------------------------------------------------------------------------
__global__ __launch_bounds__(256, 2)
void qkv_zf(const __bf16* __restrict__ xn_b, const __bf16* __restrict__ WqkvCT,
            const float* __restrict__ bqkv, __bf16* __restrict__ qkv_b,
            __bf16* __restrict__ vt, float* __restrict__ P)
{
    __shared__ uint4 As[2 * 128 * 8];
    __shared__ uint4 Bs[2 * 128 * 8];
    if (blockIdx.x < 384) {
        int bid = blockIdx.x;
        gemm_dev<128, false, false, false, false, true, true>(
            xn_b, WqkvCT, bqkv, nullptr, nullptr, nullptr, qkv_b, vt,
            3072, 1024, 1024, bid % 24, bid / 24, As, Bs);
        return;
    }
    zfill_tile(P, blockIdx.x - 384);
}

// ---------------------------------------------------------------------------
// part1_split: split-K x2 of part1 = ctx @ Wcomb. [0,256) half0 -> pA;
// [256,512) half1 -> pB. (residual/bias folded into LN2.)
// ---------------------------------------------------------------------------
__global__ __launch_bounds__(256, 2)
void part1_split(const __bf16* __restrict__ ctx_b, const __bf16* __restrict__ WcombT,
                 float* __restrict__ pA, float* __restrict__ pB)
{
    __shared__ uint4 As[2 * 128 * 8];
    __shared__ uint4 Bs[2 * 64 * 8];
    int half = blockIdx.x >> 8;
    int b2 = blockIdx.x & 255;
    const __bf16* Ah = ctx_b + half * 512;
    const __bf16* Bh = WcombT + half * 512;
    float* Cf = half ? pB : pA;
    gemm_dev<64, false, false, false, true, false, false>(
        Ah, Bh, nullptr, nullptr, nullptr, Cf, nullptr, nullptr,
        1024, 1024, 512, b2 & 15, b2 >> 4, As, Bs);
}

// ---------------------------------------------------------------------------
// ln2_fused: part1 = pA + pB + x + bcomb[col]; then LayerNorm
// ---------------------------------------------------------------------------
__global__ __launch_bounds__(256)
void ln2_fused(const float* __restrict__ pA, const float* __restrict__ pB,
               const float* __restrict__ x, const float* __restrict__ bcomb,
               const float* __restrict__ gamma, const float* __restrict__ beta,
               __bf16* __restrict__ outb, float* __restrict__ outf)
{
    __shared__ float red[8];
    int row = blockIdx.x;
    int tid = threadIdx.x;
    float4 a = ((const float4*)(pA + (size_t)row * D_MOD))[tid];
    float4 b = ((const float4*)(pB + (size_t)row * D_MOD))[tid];
    float4 xv = ((const float4*)(x + (size_t)row * D_MOD))[tid];
    float4 bc = ((const float4*)bcomb)[tid];
    float4 v;
    v.x = a.x + b.x + xv.x + bc.x;
    v.y = a.y + b.y + xv.y + bc.y;
    v.z = a.z + b.z + xv.z + bc.z;
    v.w = a.w + b.w + xv.w + bc.w;
    ln_row_v(row, v, gamma, beta, outb, outf, red);
}

// ---------------------------------------------------------------------------
// attn_flash v6: double-buffered K/V LDS with counted-vmcnt prefetch.
// Flash blocks [0,512); blocks [512,1472): P zero-fill (zid 960..1919).
// ---------------------------------------------------------------------------
__global__ __launch_bounds__(256, 2)
void attn_flash(const __bf16* __restrict__ qkv, const __bf16* __restrict__ vt,
                float* __restrict__ Obuf, __bf16* __restrict__ ctx,
                float* __restrict__ P)
{
    __shared__ char Ks[2][16384];
    __shared__ char Vs[2][16384];
    __shared__ char Plds[4][4096];
    const int tid = threadIdx.x;

    if (blockIdx.x >= 512) {
        zfill_tile(P, 960 + (int)blockIdx.x - 512);
        return;
    }

    const int lane = tid & 63;
    const int w = tid >> 6;
    const int lrow = lane & 15;
    const int g = lane >> 4;
    const int h = blockIdx.x & 15;
    const int b = 31 - ((int)blockIdx.x >> 4);
    const int qg = b * 64 + w * 16 + lrow;
    const int ntiles = (b >> 1) + 1;
    const float c1 = 0.18033688f;
    const __bf16* ksec = qkv + 1024;
    char* plB = Plds[w];

    bf16x8 qf[2];
    qf[0] = *(const bf16x8*)(qkv + (size_t)qg * 3072 + h * DK + g * 8);
    qf[1] = *(const bf16x8*)(qkv + (size_t)qg * 3072 + h * DK + 32 + g * 8);

    float m2 = -1e30f, l = 0.f;
    f32x4 acc2[4];
    #pragma unroll
    for (int i = 0; i < 4; i++) acc2[i] = (f32x4){0.f, 0.f, 0.f, 0.f};

    const int sKrow = (w << 3) + (lane >> 3);
    const int sKch = lane & 7;
    const int sVrow = (w << 2) + (lane >> 4);
    const int sVch = lane & 15;

    auto stage = [&](int kt, int tb) {
        char* KsW = Ks[tb] + w * 1024;
        char* VsW = Vs[tb] + w * 1024;
        #pragma unroll
        for (int p = 0; p < 4; p++) {
            int row = sKrow + p * 32;
            int ch = sKch ^ (row & 7);
            gload16(ksec + (size_t)(kt * 128 + row) * 3072 + h * DK + ch * 8,
                    KsW + p * 4096 + lane * 16);
        }
        #pragma unroll
        for (int p = 0; p < 4; p++) {
            int row = sVrow + p * 16;
            int ch = sVch ^ (row & 7);
            gload16(vt + (size_t)(h * DK + row) * S_LEN + kt * 128 + ch * 8,
                    VsW + p * 4096 + lane * 16);
        }
    };

    stage(0, 0);

    for (int kt = 0; kt < ntiles; kt++) {
        const int cur = kt & 1;
        if (kt + 1 < ntiles) {
            stage(kt + 1, cur ^ 1);
            asm volatile("s_waitcnt vmcnt(8)" ::: "memory");
        } else {
            asm volatile("s_waitcnt vmcnt(0)" ::: "memory");
        }
        __syncthreads();

        const char* Ksb = Ks[cur];
        const char* Vsb = Vs[cur];

        f32x4 acc[8];
        #pragma unroll
        for (int mf = 0; mf < 8; mf++) acc[mf] = (f32x4){0.f, 0.f, 0.f, 0.f};
        #pragma unroll
        for (int kk = 0; kk < 2; kk++)
            #pragma unroll
            for (int mf = 0; mf < 8; mf++) {
                int row = mf * 16 + lrow;
                bf16x8 kf = *(const bf16x8*)(Ksb + row * 128 + (((kk * 4 + g) ^ (row & 7)) << 4));
                acc[mf] = MFMA16(kf, qf[kk], acc[mf]);
            }

        float s[8][4];
        float tmx = -1e30f;
        const bool lastT = (kt == ntiles - 1);
        #pragma unroll
        for (int mf = 0; mf < 8; mf++) {
            int kvb = kt * 128 + mf * 16 + g * 4;
            #pragma unroll
            for (int r = 0; r < 4; r++) {
                float sv = acc[mf][r] * c1;
                if (lastT) sv = (kvb + r <= qg) ? sv : -1e30f;
                s[mf][r] = sv;
                tmx = fmaxf(tmx, sv);
            }
        }
        if (!__all((int)(tmx <= m2 + 6.f))) {
            float tm = fmaxf(tmx, __shfl_xor(tmx, 16));
            tm = fmaxf(tm, __shfl_xor(tm, 32));
            float nm = fmaxf(m2, tm);
            float sc = exp2f(m2 - nm);
            l *= sc;
            #pragma unroll
            for (int md = 0; md < 4; md++) acc2[md] *= sc;
            m2 = nm;
        }
        float sum = 0.f;
        #pragma unroll
        for (int mf = 0; mf < 8; mf++) {
            float p0 = exp2f(s[mf][0] - m2);
            float p1 = exp2f(s[mf][1] - m2);
            float p2 = exp2f(s[mf][2] - m2);
            float p3 = exp2f(s[mf][3] - m2);
            sum += (p0 + p1) + (p2 + p3);
            uint2 pk;
            pk.x = pack_bf16x2(p0, p1);
            pk.y = pack_bf16x2(p2, p3);
            *(uint2*)(plB + ((lrow * 256 + mf * 32 + g * 8) ^ ((lrow & 7) << 4))) = pk;
        }
        l += sum;

        #pragma unroll
        for (int ks = 0; ks < 4; ks++) {
            bf16x8 pf = *(bf16x8*)(plB + ((lrow * 256 + ks * 64 + g * 16) ^ ((lrow & 7) << 4)));
            #pragma unroll
            for (int md = 0; md < 4; md++) {
                int row = md * 16 + lrow;
                bf16x8 vf = *(const bf16x8*)(Vsb + row * 256 + (((ks * 4 + g) ^ (row & 7)) << 4));
                acc2[md] = MFMA16(vf, pf, acc2[md]);
            }
        }
        __syncthreads();
    }

    l += __shfl_xor(l, 16);
    l += __shfl_xor(l, 32);
    float li = 1.f / l;
    if (lane < 16)
        Obuf[h * S_LEN + qg] = -m2 - log2f(l);
    #pragma unroll
    for (int md = 0; md < 4; md++) {
        uint2 pk;
        pk.x = pack_bf16x2(acc2[md][0] * li, acc2[md][1] * li);
        pk.y = pack_bf16x2(acc2[md][2] * li, acc2[md][3] * li);
        *(uint2*)(ctx + (size_t)qg * D_MOD + h * DK + md * 16 + g * 4) = pk;
    }
}

// ---------------------------------------------------------------------------
// ff1_pwrite: [0,512) ff1 GEMM; [512,1600) P tiles for heads [0,8)
// ---------------------------------------------------------------------------
__global__ __launch_bounds__(256, 2)
void ff1_pwrite(const __bf16* __restrict__ A, const __bf16* __restrict__ BT,
                const float* __restrict__ bias, __bf16* __restrict__ Cb,
                const __bf16* __restrict__ qkv, const float* __restrict__ Obuf,
                float* __restrict__ P)
{
    __shared__ uint4 As[2 * 128 * 8];
    __shared__ uint4 Bs[2 * 128 * 8];
    if (blockIdx.x < 512) {
        int bid = blockIdx.x;
        gemm_dev<128, true, false, false, false, true, false>(
            A, BT, bias, nullptr, nullptr, nullptr, Cb, nullptr,
            D_FF, 1024, 1024, bid & 31, bid >> 5, As, Bs);
        return;
    }
    int idp = blockIdx.x - 512;      // [0,1088)
    int h = idp / 136;
    int tt = idp - h * 136;
    int qt = 0;
    while (tt > qt) { tt -= qt + 1; qt++; }
    pwrite_tile(qkv, Obuf, P, h, qt, tt);
}

// ---------------------------------------------------------------------------
// ff2_pwrite: [0,512) ff2 split-K halves; [512,1600) P tiles heads [8,16)
// ---------------------------------------------------------------------------
__global__ __launch_bounds__(256, 2)
void ff2_pwrite(const __bf16* __restrict__ ff1_b, const __bf16* __restrict__ Wf2T,
                float* __restrict__ partA, float* __restrict__ partB,
                const __bf16* __restrict__ qkv, const float* __restrict__ Obuf,
                float* __restrict__ P)
{
    __shared__ uint4 As[2 * 128 * 8];
    __shared__ uint4 Bs[2 * 64 * 8];
    if (blockIdx.x < 512) {
        int half = blockIdx.x >> 8;
        int b2 = blockIdx.x & 255;
        const __bf16* Ah = ff1_b + half * 2048;
        const __bf16* Bh = Wf2T + half * 2048;
        float* Cf = half ? partB : partA;
        gemm_dev<64, false, false, false, true, false, false>(
            Ah, Bh, nullptr, nullptr, nullptr, Cf, nullptr, nullptr,
            1024, 4096, 2048, b2 & 15, b2 >> 4, As, Bs);
        return;
    }
    int idp = blockIdx.x - 512;      // [0,1088)
    int h = 8 + idp / 136;
    int tt = idp - (idp / 136) * 136;
    int qt = 0;
    while (tt > qt) { tt -= qt + 1; qt++; }
    pwrite_tile(qkv, Obuf, P, h, qt, tt);
}

// ---------------------------------------------------------------------------
// ff2_reduce: out = partA + partB + norm2 + bf2
// ---------------------------------------------------------------------------
__global__ __launch_bounds__(256)
void ff2_reduce(const float* __restrict__ partA, const float* __restrict__ partB,
                const float* __restrict__ norm2f, const float* __restrict__ bf2,
                float* __restrict__ outp)
{
    int idx = blockIdx.x * 256 + threadIdx.x;
    int col = (idx * 4) & 1023;
    f32x4 a = *(const f32x4*)(partA + (size_t)idx * 4);
    f32x4 b = *(const f32x4*)(partB + (size_t)idx * 4);
    f32x4 n = *(const f32x4*)(norm2f + (size_t)idx * 4);
    f32x4 bb = *(const f32x4*)(bf2 + col);
    f32x4 o = a + b + n + bb;
    *(f32x4*)(outp + (size_t)idx * 4) = o;
}

// ---------------------------------------------------------------------------
extern "C" void kernel_launch(void* const* d_in, const int* in_sizes, int n_in,
                              void* d_out, int out_size, void* d_ws, size_t ws_size,
                              hipStream_t stream)
{
    const float* x     = (const float*)d_in[0];
    const float* g1    = (const float*)d_in[1];
    const float* beta1 = (const float*)d_in[2];
    const float* W_in  = (const float*)d_in[3];
    const float* b_in  = (const float*)d_in[4];
    const float* Wq    = (const float*)d_in[5];
    const float* bq    = (const float*)d_in[6];
    const float* Wk    = (const float*)d_in[7];
    const float* bk    = (const float*)d_in[8];
    const float* Wv    = (const float*)d_in[9];
    const float* bv    = (const float*)d_in[10];
    const float* Wo    = (const float*)d_in[11];
    const float* bo    = (const float*)d_in[12];
    const float* W2    = (const float*)d_in[13];
    const float* b2    = (const float*)d_in[14];
    const float* g2    = (const float*)d_in[15];
    const float* beta2 = (const float*)d_in[16];
    const float* Wf1   = (const float*)d_in[17];
    const float* bf1   = (const float*)d_in[18];
    const float* Wf2   = (const float*)d_in[19];
    const float* bf2   = (const float*)d_in[20];

    float* outp = (float*)d_out;                    // [2048][1024]
    float* Pout = outp + (size_t)S_LEN * D_MOD;     // [16][2048][2048]

    char* p = (char*)d_ws;
    auto alloc = [&](size_t b) -> void* {
        void* r = (void*)p;
        p += (b + 255) & ~(size_t)255;
        return r;
    };
    __bf16* WqkvT    = (__bf16*)alloc((size_t)3072 * 1024 * 2);
    __bf16* W2T      = (__bf16*)alloc((size_t)1024 * 1024 * 2);
    __bf16* Wf1T     = (__bf16*)alloc((size_t)D_FF * D_MOD * 2);
    __bf16* Wf2T     = (__bf16*)alloc((size_t)D_MOD * D_FF * 2);
    __bf16* WqkvCT   = (__bf16*)alloc((size_t)3072 * 1024 * 2);
    __bf16* WcombT   = (__bf16*)alloc((size_t)1024 * 1024 * 2);
    float*  bqkv     = (float*)alloc((size_t)3072 * 4);
    float*  bcomb    = (float*)alloc((size_t)1024 * 4);
    float*  biaspart = (float*)alloc((size_t)8 * 4096 * 4);
    __bf16* xn_b     = (__bf16*)alloc((size_t)S_LEN * D_MOD * 2);
    __bf16* qkv_b    = (__bf16*)alloc((size_t)S_LEN * 3072 * 2);
    __bf16* VT       = (__bf16*)alloc((size_t)N_HEADS * DK * S_LEN * 2);
    __bf16* ctx_b    = (__bf16*)alloc((size_t)S_LEN * D_MOD * 2);
    float*  part1f   = (float*)alloc((size_t)S_LEN * D_MOD * 4);
    float*  p1B      = (float*)alloc((size_t)S_LEN * D_MOD * 4);
    float*  norm2f   = (float*)alloc((size_t)S_LEN * D_MOD * 4);
    __bf16* norm2b   = (__bf16*)alloc((size_t)S_LEN * D_MOD * 2);
    __bf16* ff1_b    = (__bf16*)alloc((size_t)S_LEN * D_FF * 2);
    float*  Obuf     = (float*)alloc((size_t)N_HEADS * S_LEN * 4);
    float*  ffpartB  = (float*)alloc((size_t)S_LEN * D_MOD * 4);
    // aliases (lifetimes disjoint, stream-ordered):
    __bf16* Win_b   = (__bf16*)part1f;   // weight staging before part1_split
    __bf16* Wo_b    = (__bf16*)norm2f;   // weight staging before ln2
    float*  ffpartA = part1f;            // ff2 partial after ln2 consumed part1

    dim3 blk(256);

    prep1<<<dim3(14464), blk, 0, stream>>>(Wq, Wk, Wv, W2, Wf1, Wf2, W_in, Wo,
                                           b_in, bo, WqkvT, W2T, Wf1T, Wf2T,
                                           Win_b, Wo_b, biaspart);

    prep2<<<dim3(2576), blk, 0, stream>>>(WqkvT, Win_b, WqkvCT, W2T, Wo_b, WcombT,
                                          biaspart, bq, bk, bv, b2, bqkv, bcomb,
                                          x, g1, beta1, xn_b);

    // qkv GEMM (+ fused VT transpose) + 960 P zero-fill backfill
    qkv_zf<<<dim3(384 + 960), blk, 0, stream>>>(xn_b, WqkvCT, bqkv, qkv_b, VT, Pout);

    // flash attention (dbuf prefetch) + remaining 960 zero-fill backfill
    attn_flash<<<dim3(512 + 960), blk, 0, stream>>>(qkv_b, VT, Obuf, ctx_b, Pout);

    // part1 split-K x2 (residual+bias folded into LN2)
    part1_split<<<dim3(512), blk, 0, stream>>>(ctx_b, WcombT, part1f, p1B);

    ln2_fused<<<S_LEN, blk, 0, stream>>>(part1f, p1B, x, bcomb, g2, beta2,
                                         norm2b, norm2f);

    ff1_pwrite<<<dim3(512 + 1088), blk, 0, stream>>>(
        norm2b, Wf1T, bf1, ff1_b, qkv_b, Obuf, Pout);

    ff2_pwrite<<<dim3(512 + 1088), blk, 0, stream>>>(
        ff1_b, Wf2T, ffpartA, ffpartB, qkv_b, Obuf, Pout);

    ff2_reduce<<<dim3(2048), blk, 0, stream>>>(ffpartA, ffpartB, norm2f, bf2, outp);
}

// Round 14
// 252.267 us; speedup vs baseline: 1.0603x; 1.0603x over previous
//
#include <hip/hip_runtime.h>
#include <hip/hip_bf16.h>
#include <cstdint>

#define S_LEN 2048
#define D_MOD 1024
#define N_HEADS 16
#define DK 64
#define D_FF 4096

typedef __bf16 bf16x8 __attribute__((ext_vector_type(8)));
typedef float f32x4 __attribute__((ext_vector_type(4)));

#define MFMA16(a, b, c) __builtin_amdgcn_mfma_f32_16x16x32_bf16((a), (b), (c), 0, 0, 0)

__device__ inline unsigned pack_bf16x2(float a, float b)
{
    unsigned short ua = __builtin_bit_cast(unsigned short, (__bf16)a);
    unsigned short ub = __builtin_bit_cast(unsigned short, (__bf16)b);
    return (unsigned)ua | ((unsigned)ub << 16);
}

// async global->LDS, 16B per lane; LDS dest must equal waveBase + lane*16
__device__ inline void gload16(const void* g, void* l)
{
    __builtin_amdgcn_global_load_lds(
        (const __attribute__((address_space(1))) unsigned int*)g,
        (__attribute__((address_space(3))) unsigned int*)l, 16, 0, 0);
}

// ---------------------------------------------------------------------------
// Shared GEMM block body (single-buffered — round-12 proven version).
// ---------------------------------------------------------------------------
template<int BN, bool RELU, bool RES, bool RES2, bool WF32, bool WBF16, bool WVT>
__device__ __forceinline__
void gemm_dev(const __bf16* __restrict__ A, const __bf16* __restrict__ BT,
              const float* __restrict__ bias, const float* __restrict__ res,
              const float* __restrict__ res2,
              float* __restrict__ Cf, __bf16* __restrict__ Cb,
              __bf16* __restrict__ vt,
              int N, int Kst, int Klp, int bx, int by,
              uint4* As, uint4* Bs)
{
    constexpr int NFRAG = BN / 32;
    const int tid = threadIdx.x;
    const int lane = tid & 63;
    const int w = tid >> 6;
    const int lrow = lane & 15;
    const int g = lane >> 4;
    const int bm = by * 128;
    const int bn = bx * BN;
    const int wrow = (w >> 1) * 64;
    const int wcol = (w & 1) * (BN / 2);

    f32x4 acc[4][NFRAG];
    for (int m = 0; m < 4; m++)
        for (int n = 0; n < NFRAG; n++)
            acc[m][n] = (f32x4){0.f, 0.f, 0.f, 0.f};

    const int srow = tid >> 3;
    const int sc = tid & 7;
    const __bf16* Ag = A + (size_t)(bm + srow) * Kst + sc * 8;
    const __bf16* Bg = BT + (size_t)(bn + srow) * Kst + sc * 8;

    for (int kt = 0; kt < Klp; kt += 64) {
        __syncthreads();
        #pragma unroll
        for (int p = 0; p < 4; p++)
            gload16(Ag + (size_t)(p * 32) * Kst + kt, &As[(srow + p * 32) * 8 + sc]);
        #pragma unroll
        for (int p = 0; p < NFRAG; p++)
            gload16(Bg + (size_t)(p * 32) * Kst + kt, &Bs[(srow + p * 32) * 8 + sc]);
        asm volatile("s_waitcnt vmcnt(0)" ::: "memory");
        __syncthreads();
        #pragma unroll
        for (int kk = 0; kk < 2; kk++) {
            bf16x8 af[4], bfr[NFRAG];
            int c = kk * 4 + g;
            #pragma unroll
            for (int m = 0; m < 4; m++)
                af[m] = __builtin_bit_cast(bf16x8, As[(wrow + m * 16 + lrow) * 8 + c]);
            #pragma unroll
            for (int n = 0; n < NFRAG; n++)
                bfr[n] = __builtin_bit_cast(bf16x8, Bs[(wcol + n * 16 + lrow) * 8 + c]);
            #pragma unroll
            for (int m = 0; m < 4; m++)
                #pragma unroll
                for (int n = 0; n < NFRAG; n++)
                    acc[m][n] = MFMA16(af[m], bfr[n], acc[m][n]);
        }
    }

    for (int n = 0; n < NFRAG; n++) {
        int col = bn + wcol + n * 16 + lrow;
        float bval = bias ? bias[col] : 0.f;
        for (int m = 0; m < 4; m++) {
            int row0 = bm + wrow + m * 16 + g * 4;
            float vv[4];
            for (int r = 0; r < 4; r++) {
                int row = row0 + r;
                float v = acc[m][n][r] + bval;
                if (RELU) v = fmaxf(v, 0.f);
                if (RES) v += res[(size_t)row * N + col];
                if (RES2) v += res2[(size_t)row * N + col];
                vv[r] = v;
                if (WF32) Cf[(size_t)row * N + col] = v;
                if (WBF16) Cb[(size_t)row * N + col] = (__bf16)v;
            }
            if (WVT && col >= 2048) {
                uint2 pk;
                pk.x = pack_bf16x2(vv[0], vv[1]);
                pk.y = pack_bf16x2(vv[2], vv[3]);
                *(uint2*)(vt + (size_t)(col - 2048) * S_LEN + row0) = pk;
            }
        }
    }
}

// ---------------------------------------------------------------------------
// LayerNorm row body (value-input variant)
// ---------------------------------------------------------------------------
__device__ __forceinline__
void ln_row_v(int row, float4 v, const float* __restrict__ gamma,
              const float* __restrict__ beta, __bf16* __restrict__ outb,
              float* __restrict__ outf, float* red)
{
    int tid = threadIdx.x;
    float s = v.x + v.y + v.z + v.w;
    float sq = v.x * v.x + v.y * v.y + v.z * v.z + v.w * v.w;
    for (int off = 32; off; off >>= 1) {
        s += __shfl_down(s, off);
        sq += __shfl_down(sq, off);
    }
    int wid = tid >> 6;
    if ((tid & 63) == 0) { red[wid] = s; red[wid + 4] = sq; }
    __syncthreads();
    s = red[0] + red[1] + red[2] + red[3];
    sq = red[4] + red[5] + red[6] + red[7];
    float mean = s * (1.f / D_MOD);
    float var = fmaxf(sq * (1.f / D_MOD) - mean * mean, 0.f);
    float inv = 1.f / (sqrtf(var) + 1e-6f);
    float4 gv = ((const float4*)gamma)[tid];
    float4 bv = ((const float4*)beta)[tid];
    float y0 = gv.x * ((v.x - mean) * inv) + bv.x;
    float y1 = gv.y * ((v.y - mean) * inv) + bv.y;
    float y2 = gv.z * ((v.z - mean) * inv) + bv.z;
    float y3 = gv.w * ((v.w - mean) * inv) + bv.w;
    uint2 pk;
    pk.x = pack_bf16x2(y0, y1);
    pk.y = pack_bf16x2(y2, y3);
    ((uint2*)(outb + (size_t)row * D_MOD))[tid] = pk;
    if (outf) {
        float4 o = {y0, y1, y2, y3};
        ((float4*)(outf + (size_t)row * D_MOD))[tid] = o;
    }
}

__device__ __forceinline__
void ln_row(int row, const float* __restrict__ x, const float* __restrict__ gamma,
            const float* __restrict__ beta, __bf16* __restrict__ outb,
            float* __restrict__ outf, float* red)
{
    float4 v = ((const float4*)(x + (size_t)row * D_MOD))[threadIdx.x];
    ln_row_v(row, v, gamma, beta, outb, outf, red);
}

// ---------------------------------------------------------------------------
// P tile write body (kt <= qt)
// ---------------------------------------------------------------------------
__device__ __forceinline__
void pwrite_tile(const __bf16* __restrict__ qkv, const float* __restrict__ Obuf,
                 float* __restrict__ P, int h, int qt, int kt)
{
    const int tid = threadIdx.x;
    const int lane = tid & 63;
    const int w = tid >> 6;
    const int lrow = lane & 15;
    const int g = lane >> 4;
    const float c1 = 0.18033688f;
    const __bf16* ksec = qkv + 1024;
    const size_t Pb = (size_t)h * S_LEN * S_LEN;

    bf16x8 qfr[2][2];
    #pragma unroll
    for (int qq = 0; qq < 2; qq++)
        #pragma unroll
        for (int kk = 0; kk < 2; kk++)
            qfr[qq][kk] = *(const bf16x8*)(qkv +
                (size_t)(qt * 128 + w * 32 + qq * 16 + lrow) * 3072 + h * DK + kk * 32 + g * 8);

    f32x4 acc[2][8];
    #pragma unroll
    for (int qq = 0; qq < 2; qq++)
        #pragma unroll
        for (int mf = 0; mf < 8; mf++) acc[qq][mf] = (f32x4){0.f, 0.f, 0.f, 0.f};
    #pragma unroll
    for (int kk = 0; kk < 2; kk++) {
        #pragma unroll
        for (int mf = 0; mf < 8; mf++) {
            bf16x8 kf = *(const bf16x8*)(ksec +
                (size_t)(kt * 128 + mf * 16 + lrow) * 3072 + h * DK + kk * 32 + g * 8);
            acc[0][mf] = MFMA16(kf, qfr[0][kk], acc[0][mf]);
            acc[1][mf] = MFMA16(kf, qfr[1][kk], acc[1][mf]);
        }
    }

    #pragma unroll
    for (int qq = 0; qq < 2; qq++) {
        int q = qt * 128 + w * 32 + qq * 16 + lrow;
        float offv = Obuf[h * S_LEN + q];
        float* prow = P + Pb + (size_t)q * S_LEN;
        if (kt == qt) {
            #pragma unroll
            for (int mf = 0; mf < 8; mf++) {
                int kvb = kt * 128 + mf * 16 + g * 4;
                f32x4 st;
                st[0] = (kvb + 0 <= q) ? exp2f(acc[qq][mf][0] * c1 + offv) : 0.f;
                st[1] = (kvb + 1 <= q) ? exp2f(acc[qq][mf][1] * c1 + offv) : 0.f;
                st[2] = (kvb + 2 <= q) ? exp2f(acc[qq][mf][2] * c1 + offv) : 0.f;
                st[3] = (kvb + 3 <= q) ? exp2f(acc[qq][mf][3] * c1 + offv) : 0.f;
                __builtin_nontemporal_store(st, (f32x4*)(prow + kvb));
            }
        } else {
            #pragma unroll
            for (int mf = 0; mf < 8; mf++) {
                int kvb = kt * 128 + mf * 16 + g * 4;
                f32x4 st;
                st[0] = exp2f(acc[qq][mf][0] * c1 + offv);
                st[1] = exp2f(acc[qq][mf][1] * c1 + offv);
                st[2] = exp2f(acc[qq][mf][2] * c1 + offv);
                st[3] = exp2f(acc[qq][mf][3] * c1 + offv);
                __builtin_nontemporal_store(st, (f32x4*)(prow + kvb));
            }
        }
    }
}

// zero-fill one strict-upper-triangle 128x128 P tile, zid in [0,1920)
__device__ __forceinline__
void zfill_tile(float* __restrict__ P, int zid)
{
    int tid = threadIdx.x;
    int h = zid / 120;
    int pr = zid - h * 120;
    int qt = 0, acc = 0;
    while (pr >= acc + 15 - qt) { acc += 15 - qt; qt++; }
    int kt = qt + 1 + (pr - acc);
    f32x4 z = {0.f, 0.f, 0.f, 0.f};
    float* base = P + (size_t)h * S_LEN * S_LEN + (size_t)(qt * 128) * S_LEN + kt * 128;
    #pragma unroll
    for (int i = 0; i < 16; i++) {
        int idx = i * 256 + tid;
        int row = idx >> 5, c = idx & 31;
        __builtin_nontemporal_store(z, (f32x4*)(base + (size_t)row * S_LEN + c * 4));
    }
}

// ---------------------------------------------------------------------------
// prep1: [0,12288) weight transposes; [12288,14336) converts; [14336,14464)
// bias_stage1 partials.
// ---------------------------------------------------------------------------
__global__ __launch_bounds__(256)
void prep1(const float* __restrict__ Wq, const float* __restrict__ Wk,
           const float* __restrict__ Wv, const float* __restrict__ W2,
           const float* __restrict__ Wf1, const float* __restrict__ Wf2,
           const float* __restrict__ W_in, const float* __restrict__ Wo,
           const float* __restrict__ b_in, const float* __restrict__ bo,
           __bf16* __restrict__ WqkvT, __bf16* __restrict__ W2T,
           __bf16* __restrict__ Wf1T, __bf16* __restrict__ Wf2T,
           __bf16* __restrict__ Win_b, __bf16* __restrict__ Wo_b,
           float* __restrict__ part)
{
    __shared__ float tile[32][33];
    int id = blockIdx.x;
    int tid = threadIdx.x;
    if (id < 12288) {
        const float* W; __bf16* WT; int K, N, n0, k0;
        if (id < 4096) {
            int m = id >> 10; id &= 1023;
            K = 1024; N = 1024;
            n0 = (id & 31) * 32; k0 = (id >> 5) * 32;
            W = m == 0 ? Wq : (m == 1 ? Wk : (m == 2 ? Wv : W2));
            WT = m == 3 ? W2T : WqkvT + (size_t)m * 1024 * 1024;
        } else if (id < 8192) {
            id -= 4096;
            K = 1024; N = 4096;
            n0 = (id & 127) * 32; k0 = (id >> 7) * 32;
            W = Wf1; WT = Wf1T;
        } else {
            id -= 8192;
            K = 4096; N = 1024;
            n0 = (id & 31) * 32; k0 = (id >> 5) * 32;
            W = Wf2; WT = Wf2T;
        }
        int tx = tid & 31, ty = tid >> 5;
        for (int i = 0; i < 4; i++)
            tile[ty + i * 8][tx] = W[(size_t)(k0 + ty + i * 8) * N + n0 + tx];
        __syncthreads();
        for (int i = 0; i < 4; i++)
            WT[(size_t)(n0 + ty + i * 8) * K + k0 + tx] = (__bf16)tile[tx][ty + i * 8];
        return;
    }
    id -= 12288;
    if (id < 2048) {
        const float* W = id < 1024 ? W_in : Wo;
        __bf16* o = id < 1024 ? Win_b : Wo_b;
        int i = (id & 1023) * 256 + tid;
        float4 v = ((const float4*)W)[i];
        uint2 pk;
        pk.x = pack_bf16x2(v.x, v.y);
        pk.y = pack_bf16x2(v.z, v.w);
        ((uint2*)o)[i] = pk;
        return;
    }
    id -= 2048;
    {
        int n = (id & 15) * 256 + tid;
        int kc = id >> 4;
        int sel = n >> 10, col = n & 1023;
        const float* W = sel == 0 ? Wq : (sel == 1 ? Wk : (sel == 2 ? Wv : W2));
        const float* src = sel < 3 ? b_in : bo;
        float s = 0.f;
        for (int k = kc * 128; k < kc * 128 + 128; k++)
            s += src[k] * W[(size_t)k * 1024 + col];
        part[kc * 4096 + n] = s;
    }
}

// ---------------------------------------------------------------------------
// prep2: [0,384) WqkvCT gemm; [384,512) WcombT gemm; [512,528) bias_stage2;
// [528,2576) LN1 rows.
// ---------------------------------------------------------------------------
__global__ __launch_bounds__(256, 2)
void prep2(const __bf16* __restrict__ WqkvT, const __bf16* __restrict__ Win_b,
           __bf16* __restrict__ WqkvCT,
           const __bf16* __restrict__ W2T, const __bf16* __restrict__ Wo_b,
           __bf16* __restrict__ WcombT,
           const float* __restrict__ part,
           const float* __restrict__ bq, const float* __restrict__ bk,
           const float* __restrict__ bv, const float* __restrict__ b2,
           float* __restrict__ bqkv, float* __restrict__ bcomb,
           const float* __restrict__ x, const float* __restrict__ g1,
           const float* __restrict__ beta1, __bf16* __restrict__ xn_b)
{
    __shared__ uint4 As[128 * 8];
    __shared__ uint4 Bs[64 * 8];
    int id = blockIdx.x;
    int tid = threadIdx.x;
    if (id < 384) {
        gemm_dev<64, false, false, false, false, true, false>(
            WqkvT, Win_b, nullptr, nullptr, nullptr, nullptr, WqkvCT, nullptr,
            1024, 1024, 1024, id & 15, id >> 4, As, Bs);
        return;
    }
    id -= 384;
    if (id < 128) {
        gemm_dev<64, false, false, false, false, true, false>(
            W2T, Wo_b, nullptr, nullptr, nullptr, nullptr, WcombT, nullptr,
            1024, 1024, 1024, id & 15, id >> 4, As, Bs);
        return;
    }
    id -= 128;
    if (id < 16) {
        int n = id * 256 + tid;
        int sel = n >> 10, col = n & 1023;
        float s = sel == 0 ? bq[col] : (sel == 1 ? bk[col] : (sel == 2 ? bv[col] : b2[col]));
        for (int kc = 0; kc < 8; kc++) s += part[kc * 4096 + n];
        if (n < 3072) bqkv[n] = s; else bcomb[col] = s;
        return;
    }
    id -= 16;
    ln_row(id, x, g1, beta1, xn_b, nullptr, (float*)As);
}

// ---------------------------------------------------------------------------
// qkv_zf: [0,384) qkv GEMM (with fused VT epilogue); [384,1344) P zero-fill
// ---------------------------------------------------------------------------
__global__ __launch_bounds__(256, 2)
void qkv_zf(const __bf16* __restrict__ xn_b, const __bf16* __restrict__ WqkvCT,
            const float* __restrict__ bqkv, __bf16* __restrict__ qkv_b,
            __bf16* __restrict__ vt, float* __restrict__ P)
{
    __shared__ uint4 As[128 * 8];
    __shared__ uint4 Bs[128 * 8];
    if (blockIdx.x < 384) {
        int bid = blockIdx.x;
        gemm_dev<128, false, false, false, false, true, true>(
            xn_b, WqkvCT, bqkv, nullptr, nullptr, nullptr, qkv_b, vt,
            3072, 1024, 1024, bid % 24, bid / 24, As, Bs);
        return;
    }
    zfill_tile(P, blockIdx.x - 384);
}

// ---------------------------------------------------------------------------
// part1_split: split-K x2 of part1 = ctx @ Wcomb. [0,256) half0 -> pA;
// [256,512) half1 -> pB. (residual/bias folded into LN2.)
// ---------------------------------------------------------------------------
__global__ __launch_bounds__(256, 2)
void part1_split(const __bf16* __restrict__ ctx_b, const __bf16* __restrict__ WcombT,
                 float* __restrict__ pA, float* __restrict__ pB)
{
    __shared__ uint4 As[128 * 8];
    __shared__ uint4 Bs[64 * 8];
    int half = blockIdx.x >> 8;
    int b2 = blockIdx.x & 255;
    const __bf16* Ah = ctx_b + half * 512;
    const __bf16* Bh = WcombT + half * 512;
    float* Cf = half ? pB : pA;
    gemm_dev<64, false, false, false, true, false, false>(
        Ah, Bh, nullptr, nullptr, nullptr, Cf, nullptr, nullptr,
        1024, 1024, 512, b2 & 15, b2 >> 4, As, Bs);
}

// ---------------------------------------------------------------------------
// ln2_fused: part1 = pA + pB + x + bcomb[col]; then LayerNorm
// ---------------------------------------------------------------------------
__global__ __launch_bounds__(256)
void ln2_fused(const float* __restrict__ pA, const float* __restrict__ pB,
               const float* __restrict__ x, const float* __restrict__ bcomb,
               const float* __restrict__ gamma, const float* __restrict__ beta,
               __bf16* __restrict__ outb, float* __restrict__ outf)
{
    __shared__ float red[8];
    int row = blockIdx.x;
    int tid = threadIdx.x;
    float4 a = ((const float4*)(pA + (size_t)row * D_MOD))[tid];
    float4 b = ((const float4*)(pB + (size_t)row * D_MOD))[tid];
    float4 xv = ((const float4*)(x + (size_t)row * D_MOD))[tid];
    float4 bc = ((const float4*)bcomb)[tid];
    float4 v;
    v.x = a.x + b.x + xv.x + bc.x;
    v.y = a.y + b.y + xv.y + bc.y;
    v.z = a.z + b.z + xv.z + bc.z;
    v.w = a.w + b.w + xv.w + bc.w;
    ln_row_v(row, v, gamma, beta, outb, outf, red);
}

// ---------------------------------------------------------------------------
// attn_flash v6: double-buffered K/V LDS with counted-vmcnt prefetch.
// Flash blocks [0,512); blocks [512,1472): P zero-fill (zid 960..1919).
// ---------------------------------------------------------------------------
__global__ __launch_bounds__(256, 2)
void attn_flash(const __bf16* __restrict__ qkv, const __bf16* __restrict__ vt,
                float* __restrict__ Obuf, __bf16* __restrict__ ctx,
                float* __restrict__ P)
{
    __shared__ char Ks[2][16384];
    __shared__ char Vs[2][16384];
    __shared__ char Plds[4][4096];
    const int tid = threadIdx.x;

    if (blockIdx.x >= 512) {
        zfill_tile(P, 960 + (int)blockIdx.x - 512);
        return;
    }

    const int lane = tid & 63;
    const int w = tid >> 6;
    const int lrow = lane & 15;
    const int g = lane >> 4;
    const int h = blockIdx.x & 15;
    const int b = 31 - ((int)blockIdx.x >> 4);
    const int qg = b * 64 + w * 16 + lrow;
    const int ntiles = (b >> 1) + 1;
    const float c1 = 0.18033688f;
    const __bf16* ksec = qkv + 1024;
    char* plB = Plds[w];

    bf16x8 qf[2];
    qf[0] = *(const bf16x8*)(qkv + (size_t)qg * 3072 + h * DK + g * 8);
    qf[1] = *(const bf16x8*)(qkv + (size_t)qg * 3072 + h * DK + 32 + g * 8);

    float m2 = -1e30f, l = 0.f;
    f32x4 acc2[4];
    #pragma unroll
    for (int i = 0; i < 4; i++) acc2[i] = (f32x4){0.f, 0.f, 0.f, 0.f};

    const int sKrow = (w << 3) + (lane >> 3);
    const int sKch = lane & 7;
    const int sVrow = (w << 2) + (lane >> 4);
    const int sVch = lane & 15;

    auto stage = [&](int kt, int tb) {
        char* KsW = Ks[tb] + w * 1024;
        char* VsW = Vs[tb] + w * 1024;
        #pragma unroll
        for (int p = 0; p < 4; p++) {
            int row = sKrow + p * 32;
            int ch = sKch ^ (row & 7);
            gload16(ksec + (size_t)(kt * 128 + row) * 3072 + h * DK + ch * 8,
                    KsW + p * 4096 + lane * 16);
        }
        #pragma unroll
        for (int p = 0; p < 4; p++) {
            int row = sVrow + p * 16;
            int ch = sVch ^ (row & 7);
            gload16(vt + (size_t)(h * DK + row) * S_LEN + kt * 128 + ch * 8,
                    VsW + p * 4096 + lane * 16);
        }
    };

    stage(0, 0);

    for (int kt = 0; kt < ntiles; kt++) {
        const int cur = kt & 1;
        if (kt + 1 < ntiles) {
            stage(kt + 1, cur ^ 1);
            asm volatile("s_waitcnt vmcnt(8)" ::: "memory");
        } else {
            asm volatile("s_waitcnt vmcnt(0)" ::: "memory");
        }
        __syncthreads();

        const char* Ksb = Ks[cur];
        const char* Vsb = Vs[cur];

        f32x4 acc[8];
        #pragma unroll
        for (int mf = 0; mf < 8; mf++) acc[mf] = (f32x4){0.f, 0.f, 0.f, 0.f};
        #pragma unroll
        for (int kk = 0; kk < 2; kk++)
            #pragma unroll
            for (int mf = 0; mf < 8; mf++) {
                int row = mf * 16 + lrow;
                bf16x8 kf = *(const bf16x8*)(Ksb + row * 128 + (((kk * 4 + g) ^ (row & 7)) << 4));
                acc[mf] = MFMA16(kf, qf[kk], acc[mf]);
            }

        float s[8][4];
        float tmx = -1e30f;
        const bool lastT = (kt == ntiles - 1);
        #pragma unroll
        for (int mf = 0; mf < 8; mf++) {
            int kvb = kt * 128 + mf * 16 + g * 4;
            #pragma unroll
            for (int r = 0; r < 4; r++) {
                float sv = acc[mf][r] * c1;
                if (lastT) sv = (kvb + r <= qg) ? sv : -1e30f;
                s[mf][r] = sv;
                tmx = fmaxf(tmx, sv);
            }
        }
        if (!__all((int)(tmx <= m2 + 6.f))) {
            float tm = fmaxf(tmx, __shfl_xor(tmx, 16));
            tm = fmaxf(tm, __shfl_xor(tm, 32));
            float nm = fmaxf(m2, tm);
            float sc = exp2f(m2 - nm);
            l *= sc;
            #pragma unroll
            for (int md = 0; md < 4; md++) acc2[md] *= sc;
            m2 = nm;
        }
        float sum = 0.f;
        #pragma unroll
        for (int mf = 0; mf < 8; mf++) {
            float p0 = exp2f(s[mf][0] - m2);
            float p1 = exp2f(s[mf][1] - m2);
            float p2 = exp2f(s[mf][2] - m2);
            float p3 = exp2f(s[mf][3] - m2);
            sum += (p0 + p1) + (p2 + p3);
            uint2 pk;
            pk.x = pack_bf16x2(p0, p1);
            pk.y = pack_bf16x2(p2, p3);
            *(uint2*)(plB + ((lrow * 256 + mf * 32 + g * 8) ^ ((lrow & 7) << 4))) = pk;
        }
        l += sum;

        #pragma unroll
        for (int ks = 0; ks < 4; ks++) {
            bf16x8 pf = *(bf16x8*)(plB + ((lrow * 256 + ks * 64 + g * 16) ^ ((lrow & 7) << 4)));
            #pragma unroll
            for (int md = 0; md < 4; md++) {
                int row = md * 16 + lrow;
                bf16x8 vf = *(const bf16x8*)(Vsb + row * 256 + (((ks * 4 + g) ^ (row & 7)) << 4));
                acc2[md] = MFMA16(vf, pf, acc2[md]);
            }
        }
        __syncthreads();
    }

    l += __shfl_xor(l, 16);
    l += __shfl_xor(l, 32);
    float li = 1.f / l;
    if (lane < 16)
        Obuf[h * S_LEN + qg] = -m2 - log2f(l);
    #pragma unroll
    for (int md = 0; md < 4; md++) {
        uint2 pk;
        pk.x = pack_bf16x2(acc2[md][0] * li, acc2[md][1] * li);
        pk.y = pack_bf16x2(acc2[md][2] * li, acc2[md][3] * li);
        *(uint2*)(ctx + (size_t)qg * D_MOD + h * DK + md * 16 + g * 4) = pk;
    }
}

// ---------------------------------------------------------------------------
// ff1_pwrite: [0,512) ff1 GEMM; [512,1600) P tiles for heads [0,8)
// ---------------------------------------------------------------------------
__global__ __launch_bounds__(256, 2)
void ff1_pwrite(const __bf16* __restrict__ A, const __bf16* __restrict__ BT,
                const float* __restrict__ bias, __bf16* __restrict__ Cb,
                const __bf16* __restrict__ qkv, const float* __restrict__ Obuf,
                float* __restrict__ P)
{
    __shared__ uint4 As[128 * 8];
    __shared__ uint4 Bs[128 * 8];
    if (blockIdx.x < 512) {
        int bid = blockIdx.x;
        gemm_dev<128, true, false, false, false, true, false>(
            A, BT, bias, nullptr, nullptr, nullptr, Cb, nullptr,
            D_FF, 1024, 1024, bid & 31, bid >> 5, As, Bs);
        return;
    }
    int idp = blockIdx.x - 512;      // [0,1088)
    int h = idp / 136;
    int tt = idp - h * 136;
    int qt = 0;
    while (tt > qt) { tt -= qt + 1; qt++; }
    pwrite_tile(qkv, Obuf, P, h, qt, tt);
}

// ---------------------------------------------------------------------------
// ff2_pwrite: [0,512) ff2 split-K halves; [512,1600) P tiles heads [8,16)
// ---------------------------------------------------------------------------
__global__ __launch_bounds__(256, 2)
void ff2_pwrite(const __bf16* __restrict__ ff1_b, const __bf16* __restrict__ Wf2T,
                float* __restrict__ partA, float* __restrict__ partB,
                const __bf16* __restrict__ qkv, const float* __restrict__ Obuf,
                float* __restrict__ P)
{
    __shared__ uint4 As[128 * 8];
    __shared__ uint4 Bs[64 * 8];
    if (blockIdx.x < 512) {
        int half = blockIdx.x >> 8;
        int b2 = blockIdx.x & 255;
        const __bf16* Ah = ff1_b + half * 2048;
        const __bf16* Bh = Wf2T + half * 2048;
        float* Cf = half ? partB : partA;
        gemm_dev<64, false, false, false, true, false, false>(
            Ah, Bh, nullptr, nullptr, nullptr, Cf, nullptr, nullptr,
            1024, 4096, 2048, b2 & 15, b2 >> 4, As, Bs);
        return;
    }
    int idp = blockIdx.x - 512;      // [0,1088)
    int h = 8 + idp / 136;
    int tt = idp - (idp / 136) * 136;
    int qt = 0;
    while (tt > qt) { tt -= qt + 1; qt++; }
    pwrite_tile(qkv, Obuf, P, h, qt, tt);
}

// ---------------------------------------------------------------------------
// ff2_reduce: out = partA + partB + norm2 + bf2
// ---------------------------------------------------------------------------
__global__ __launch_bounds__(256)
void ff2_reduce(const float* __restrict__ partA, const float* __restrict__ partB,
                const float* __restrict__ norm2f, const float* __restrict__ bf2,
                float* __restrict__ outp)
{
    int idx = blockIdx.x * 256 + threadIdx.x;
    int col = (idx * 4) & 1023;
    f32x4 a = *(const f32x4*)(partA + (size_t)idx * 4);
    f32x4 b = *(const f32x4*)(partB + (size_t)idx * 4);
    f32x4 n = *(const f32x4*)(norm2f + (size_t)idx * 4);
    f32x4 bb = *(const f32x4*)(bf2 + col);
    f32x4 o = a + b + n + bb;
    *(f32x4*)(outp + (size_t)idx * 4) = o;
}

// ---------------------------------------------------------------------------
extern "C" void kernel_launch(void* const* d_in, const int* in_sizes, int n_in,
                              void* d_out, int out_size, void* d_ws, size_t ws_size,
                              hipStream_t stream)
{
    const float* x     = (const float*)d_in[0];
    const float* g1    = (const float*)d_in[1];
    const float* beta1 = (const float*)d_in[2];
    const float* W_in  = (const float*)d_in[3];
    const float* b_in  = (const float*)d_in[4];
    const float* Wq    = (const float*)d_in[5];
    const float* bq    = (const float*)d_in[6];
    const float* Wk    = (const float*)d_in[7];
    const float* bk    = (const float*)d_in[8];
    const float* Wv    = (const float*)d_in[9];
    const float* bv    = (const float*)d_in[10];
    const float* Wo    = (const float*)d_in[11];
    const float* bo    = (const float*)d_in[12];
    const float* W2    = (const float*)d_in[13];
    const float* b2    = (const float*)d_in[14];
    const float* g2    = (const float*)d_in[15];
    const float* beta2 = (const float*)d_in[16];
    const float* Wf1   = (const float*)d_in[17];
    const float* bf1   = (const float*)d_in[18];
    const float* Wf2   = (const float*)d_in[19];
    const float* bf2   = (const float*)d_in[20];

    float* outp = (float*)d_out;                    // [2048][1024]
    float* Pout = outp + (size_t)S_LEN * D_MOD;     // [16][2048][2048]

    char* p = (char*)d_ws;
    auto alloc = [&](size_t b) -> void* {
        void* r = (void*)p;
        p += (b + 255) & ~(size_t)255;
        return r;
    };
    __bf16* WqkvT    = (__bf16*)alloc((size_t)3072 * 1024 * 2);
    __bf16* W2T      = (__bf16*)alloc((size_t)1024 * 1024 * 2);
    __bf16* Wf1T     = (__bf16*)alloc((size_t)D_FF * D_MOD * 2);
    __bf16* Wf2T     = (__bf16*)alloc((size_t)D_MOD * D_FF * 2);
    __bf16* WqkvCT   = (__bf16*)alloc((size_t)3072 * 1024 * 2);
    __bf16* WcombT   = (__bf16*)alloc((size_t)1024 * 1024 * 2);
    float*  bqkv     = (float*)alloc((size_t)3072 * 4);
    float*  bcomb    = (float*)alloc((size_t)1024 * 4);
    float*  biaspart = (float*)alloc((size_t)8 * 4096 * 4);
    __bf16* xn_b     = (__bf16*)alloc((size_t)S_LEN * D_MOD * 2);
    __bf16* qkv_b    = (__bf16*)alloc((size_t)S_LEN * 3072 * 2);
    __bf16* VT       = (__bf16*)alloc((size_t)N_HEADS * DK * S_LEN * 2);
    __bf16* ctx_b    = (__bf16*)alloc((size_t)S_LEN * D_MOD * 2);
    float*  part1f   = (float*)alloc((size_t)S_LEN * D_MOD * 4);
    float*  p1B      = (float*)alloc((size_t)S_LEN * D_MOD * 4);
    float*  norm2f   = (float*)alloc((size_t)S_LEN * D_MOD * 4);
    __bf16* norm2b   = (__bf16*)alloc((size_t)S_LEN * D_MOD * 2);
    __bf16* ff1_b    = (__bf16*)alloc((size_t)S_LEN * D_FF * 2);
    float*  Obuf     = (float*)alloc((size_t)N_HEADS * S_LEN * 4);
    float*  ffpartB  = (float*)alloc((size_t)S_LEN * D_MOD * 4);
    // aliases (lifetimes disjoint, stream-ordered):
    __bf16* Win_b   = (__bf16*)part1f;   // weight staging before part1_split
    __bf16* Wo_b    = (__bf16*)norm2f;   // weight staging before ln2
    float*  ffpartA = part1f;            // ff2 partial after ln2 consumed part1

    dim3 blk(256);

    prep1<<<dim3(14464), blk, 0, stream>>>(Wq, Wk, Wv, W2, Wf1, Wf2, W_in, Wo,
                                           b_in, bo, WqkvT, W2T, Wf1T, Wf2T,
                                           Win_b, Wo_b, biaspart);

    prep2<<<dim3(2576), blk, 0, stream>>>(WqkvT, Win_b, WqkvCT, W2T, Wo_b, WcombT,
                                          biaspart, bq, bk, bv, b2, bqkv, bcomb,
                                          x, g1, beta1, xn_b);

    // qkv GEMM (+ fused VT transpose) + 960 P zero-fill backfill
    qkv_zf<<<dim3(384 + 960), blk, 0, stream>>>(xn_b, WqkvCT, bqkv, qkv_b, VT, Pout);

    // flash attention (dbuf prefetch) + remaining 960 zero-fill backfill
    attn_flash<<<dim3(512 + 960), blk, 0, stream>>>(qkv_b, VT, Obuf, ctx_b, Pout);

    // part1 split-K x2 (residual+bias folded into LN2)
    part1_split<<<dim3(512), blk, 0, stream>>>(ctx_b, WcombT, part1f, p1B);

    ln2_fused<<<S_LEN, blk, 0, stream>>>(part1f, p1B, x, bcomb, g2, beta2,
                                         norm2b, norm2f);

    ff1_pwrite<<<dim3(512 + 1088), blk, 0, stream>>>(
        norm2b, Wf1T, bf1, ff1_b, qkv_b, Obuf, Pout);

    ff2_pwrite<<<dim3(512 + 1088), blk, 0, stream>>>(
        ff1_b, Wf2T, ffpartA, ffpartB, qkv_b, Obuf, Pout);

    ff2_reduce<<<dim3(2048), blk, 0, stream>>>(ffpartA, ffpartB, norm2f, bf2, outp);
}

// Round 15
// 249.118 us; speedup vs baseline: 1.0737x; 1.0126x over previous
//
#include <hip/hip_runtime.h>
#include <hip/hip_bf16.h>
#include <cstdint>

#define S_LEN 2048
#define D_MOD 1024
#define N_HEADS 16
#define DK 64
#define D_FF 4096

typedef __bf16 bf16x8 __attribute__((ext_vector_type(8)));
typedef float f32x4 __attribute__((ext_vector_type(4)));

#define MFMA16(a, b, c) __builtin_amdgcn_mfma_f32_16x16x32_bf16((a), (b), (c), 0, 0, 0)

__device__ inline unsigned pack_bf16x2(float a, float b)
{
    unsigned short ua = __builtin_bit_cast(unsigned short, (__bf16)a);
    unsigned short ub = __builtin_bit_cast(unsigned short, (__bf16)b);
    return (unsigned)ua | ((unsigned)ub << 16);
}

// async global->LDS, 16B per lane; LDS dest must equal waveBase + lane*16
__device__ inline void gload16(const void* g, void* l)
{
    __builtin_amdgcn_global_load_lds(
        (const __attribute__((address_space(1))) unsigned int*)g,
        (__attribute__((address_space(3))) unsigned int*)l, 16, 0, 0);
}

// XCD-aware swizzle: nwg must be divisible by 8. Blocks dispatched round-robin
// to 8 XCDs; same-XCD blocks get consecutive logical tiles -> L2 panel reuse.
__device__ inline int swz8(int bid, int nwg)
{
    return (bid & 7) * (nwg >> 3) + (bid >> 3);
}

// ---------------------------------------------------------------------------
// Shared GEMM block body (single-buffered — round-12 proven version).
// ---------------------------------------------------------------------------
template<int BN, bool RELU, bool RES, bool RES2, bool WF32, bool WBF16, bool WVT>
__device__ __forceinline__
void gemm_dev(const __bf16* __restrict__ A, const __bf16* __restrict__ BT,
              const float* __restrict__ bias, const float* __restrict__ res,
              const float* __restrict__ res2,
              float* __restrict__ Cf, __bf16* __restrict__ Cb,
              __bf16* __restrict__ vt,
              int N, int Kst, int Klp, int bx, int by,
              uint4* As, uint4* Bs)
{
    constexpr int NFRAG = BN / 32;
    const int tid = threadIdx.x;
    const int lane = tid & 63;
    const int w = tid >> 6;
    const int lrow = lane & 15;
    const int g = lane >> 4;
    const int bm = by * 128;
    const int bn = bx * BN;
    const int wrow = (w >> 1) * 64;
    const int wcol = (w & 1) * (BN / 2);

    f32x4 acc[4][NFRAG];
    for (int m = 0; m < 4; m++)
        for (int n = 0; n < NFRAG; n++)
            acc[m][n] = (f32x4){0.f, 0.f, 0.f, 0.f};

    const int srow = tid >> 3;
    const int sc = tid & 7;
    const __bf16* Ag = A + (size_t)(bm + srow) * Kst + sc * 8;
    const __bf16* Bg = BT + (size_t)(bn + srow) * Kst + sc * 8;

    for (int kt = 0; kt < Klp; kt += 64) {
        __syncthreads();
        #pragma unroll
        for (int p = 0; p < 4; p++)
            gload16(Ag + (size_t)(p * 32) * Kst + kt, &As[(srow + p * 32) * 8 + sc]);
        #pragma unroll
        for (int p = 0; p < NFRAG; p++)
            gload16(Bg + (size_t)(p * 32) * Kst + kt, &Bs[(srow + p * 32) * 8 + sc]);
        asm volatile("s_waitcnt vmcnt(0)" ::: "memory");
        __syncthreads();
        #pragma unroll
        for (int kk = 0; kk < 2; kk++) {
            bf16x8 af[4], bfr[NFRAG];
            int c = kk * 4 + g;
            #pragma unroll
            for (int m = 0; m < 4; m++)
                af[m] = __builtin_bit_cast(bf16x8, As[(wrow + m * 16 + lrow) * 8 + c]);
            #pragma unroll
            for (int n = 0; n < NFRAG; n++)
                bfr[n] = __builtin_bit_cast(bf16x8, Bs[(wcol + n * 16 + lrow) * 8 + c]);
            #pragma unroll
            for (int m = 0; m < 4; m++)
                #pragma unroll
                for (int n = 0; n < NFRAG; n++)
                    acc[m][n] = MFMA16(af[m], bfr[n], acc[m][n]);
        }
    }

    for (int n = 0; n < NFRAG; n++) {
        int col = bn + wcol + n * 16 + lrow;
        float bval = bias ? bias[col] : 0.f;
        for (int m = 0; m < 4; m++) {
            int row0 = bm + wrow + m * 16 + g * 4;
            float vv[4];
            for (int r = 0; r < 4; r++) {
                int row = row0 + r;
                float v = acc[m][n][r] + bval;
                if (RELU) v = fmaxf(v, 0.f);
                if (RES) v += res[(size_t)row * N + col];
                if (RES2) v += res2[(size_t)row * N + col];
                vv[r] = v;
                if (WF32) Cf[(size_t)row * N + col] = v;
                if (WBF16) Cb[(size_t)row * N + col] = (__bf16)v;
            }
            if (WVT && col >= 2048) {
                uint2 pk;
                pk.x = pack_bf16x2(vv[0], vv[1]);
                pk.y = pack_bf16x2(vv[2], vv[3]);
                *(uint2*)(vt + (size_t)(col - 2048) * S_LEN + row0) = pk;
            }
        }
    }
}

// ---------------------------------------------------------------------------
// LayerNorm row body (value-input variant)
// ---------------------------------------------------------------------------
__device__ __forceinline__
void ln_row_v(int row, float4 v, const float* __restrict__ gamma,
              const float* __restrict__ beta, __bf16* __restrict__ outb,
              float* __restrict__ outf, float* red)
{
    int tid = threadIdx.x;
    float s = v.x + v.y + v.z + v.w;
    float sq = v.x * v.x + v.y * v.y + v.z * v.z + v.w * v.w;
    for (int off = 32; off; off >>= 1) {
        s += __shfl_down(s, off);
        sq += __shfl_down(sq, off);
    }
    int wid = tid >> 6;
    if ((tid & 63) == 0) { red[wid] = s; red[wid + 4] = sq; }
    __syncthreads();
    s = red[0] + red[1] + red[2] + red[3];
    sq = red[4] + red[5] + red[6] + red[7];
    float mean = s * (1.f / D_MOD);
    float var = fmaxf(sq * (1.f / D_MOD) - mean * mean, 0.f);
    float inv = 1.f / (sqrtf(var) + 1e-6f);
    float4 gv = ((const float4*)gamma)[tid];
    float4 bv = ((const float4*)beta)[tid];
    float y0 = gv.x * ((v.x - mean) * inv) + bv.x;
    float y1 = gv.y * ((v.y - mean) * inv) + bv.y;
    float y2 = gv.z * ((v.z - mean) * inv) + bv.z;
    float y3 = gv.w * ((v.w - mean) * inv) + bv.w;
    uint2 pk;
    pk.x = pack_bf16x2(y0, y1);
    pk.y = pack_bf16x2(y2, y3);
    ((uint2*)(outb + (size_t)row * D_MOD))[tid] = pk;
    if (outf) {
        float4 o = {y0, y1, y2, y3};
        ((float4*)(outf + (size_t)row * D_MOD))[tid] = o;
    }
}

__device__ __forceinline__
void ln_row(int row, const float* __restrict__ x, const float* __restrict__ gamma,
            const float* __restrict__ beta, __bf16* __restrict__ outb,
            float* __restrict__ outf, float* red)
{
    float4 v = ((const float4*)(x + (size_t)row * D_MOD))[threadIdx.x];
    ln_row_v(row, v, gamma, beta, outb, outf, red);
}

// ---------------------------------------------------------------------------
// P tile write body (kt <= qt)
// ---------------------------------------------------------------------------
__device__ __forceinline__
void pwrite_tile(const __bf16* __restrict__ qkv, const float* __restrict__ Obuf,
                 float* __restrict__ P, int h, int qt, int kt)
{
    const int tid = threadIdx.x;
    const int lane = tid & 63;
    const int w = tid >> 6;
    const int lrow = lane & 15;
    const int g = lane >> 4;
    const float c1 = 0.18033688f;
    const __bf16* ksec = qkv + 1024;
    const size_t Pb = (size_t)h * S_LEN * S_LEN;

    bf16x8 qfr[2][2];
    #pragma unroll
    for (int qq = 0; qq < 2; qq++)
        #pragma unroll
        for (int kk = 0; kk < 2; kk++)
            qfr[qq][kk] = *(const bf16x8*)(qkv +
                (size_t)(qt * 128 + w * 32 + qq * 16 + lrow) * 3072 + h * DK + kk * 32 + g * 8);

    f32x4 acc[2][8];
    #pragma unroll
    for (int qq = 0; qq < 2; qq++)
        #pragma unroll
        for (int mf = 0; mf < 8; mf++) acc[qq][mf] = (f32x4){0.f, 0.f, 0.f, 0.f};
    #pragma unroll
    for (int kk = 0; kk < 2; kk++) {
        #pragma unroll
        for (int mf = 0; mf < 8; mf++) {
            bf16x8 kf = *(const bf16x8*)(ksec +
                (size_t)(kt * 128 + mf * 16 + lrow) * 3072 + h * DK + kk * 32 + g * 8);
            acc[0][mf] = MFMA16(kf, qfr[0][kk], acc[0][mf]);
            acc[1][mf] = MFMA16(kf, qfr[1][kk], acc[1][mf]);
        }
    }

    #pragma unroll
    for (int qq = 0; qq < 2; qq++) {
        int q = qt * 128 + w * 32 + qq * 16 + lrow;
        float offv = Obuf[h * S_LEN + q];
        float* prow = P + Pb + (size_t)q * S_LEN;
        if (kt == qt) {
            #pragma unroll
            for (int mf = 0; mf < 8; mf++) {
                int kvb = kt * 128 + mf * 16 + g * 4;
                f32x4 st;
                st[0] = (kvb + 0 <= q) ? exp2f(acc[qq][mf][0] * c1 + offv) : 0.f;
                st[1] = (kvb + 1 <= q) ? exp2f(acc[qq][mf][1] * c1 + offv) : 0.f;
                st[2] = (kvb + 2 <= q) ? exp2f(acc[qq][mf][2] * c1 + offv) : 0.f;
                st[3] = (kvb + 3 <= q) ? exp2f(acc[qq][mf][3] * c1 + offv) : 0.f;
                __builtin_nontemporal_store(st, (f32x4*)(prow + kvb));
            }
        } else {
            #pragma unroll
            for (int mf = 0; mf < 8; mf++) {
                int kvb = kt * 128 + mf * 16 + g * 4;
                f32x4 st;
                st[0] = exp2f(acc[qq][mf][0] * c1 + offv);
                st[1] = exp2f(acc[qq][mf][1] * c1 + offv);
                st[2] = exp2f(acc[qq][mf][2] * c1 + offv);
                st[3] = exp2f(acc[qq][mf][3] * c1 + offv);
                __builtin_nontemporal_store(st, (f32x4*)(prow + kvb));
            }
        }
    }
}

// zero-fill one strict-upper-triangle 128x128 P tile, zid in [0,1920)
__device__ __forceinline__
void zfill_tile(float* __restrict__ P, int zid)
{
    int tid = threadIdx.x;
    int h = zid / 120;
    int pr = zid - h * 120;
    int qt = 0, acc = 0;
    while (pr >= acc + 15 - qt) { acc += 15 - qt; qt++; }
    int kt = qt + 1 + (pr - acc);
    f32x4 z = {0.f, 0.f, 0.f, 0.f};
    float* base = P + (size_t)h * S_LEN * S_LEN + (size_t)(qt * 128) * S_LEN + kt * 128;
    #pragma unroll
    for (int i = 0; i < 16; i++) {
        int idx = i * 256 + tid;
        int row = idx >> 5, c = idx & 31;
        __builtin_nontemporal_store(z, (f32x4*)(base + (size_t)row * S_LEN + c * 4));
    }
}

// ---------------------------------------------------------------------------
// prep1: [0,12288) weight transposes; [12288,14336) converts; [14336,14464)
// bias_stage1 partials.
// ---------------------------------------------------------------------------
__global__ __launch_bounds__(256)
void prep1(const float* __restrict__ Wq, const float* __restrict__ Wk,
           const float* __restrict__ Wv, const float* __restrict__ W2,
           const float* __restrict__ Wf1, const float* __restrict__ Wf2,
           const float* __restrict__ W_in, const float* __restrict__ Wo,
           const float* __restrict__ b_in, const float* __restrict__ bo,
           __bf16* __restrict__ WqkvT, __bf16* __restrict__ W2T,
           __bf16* __restrict__ Wf1T, __bf16* __restrict__ Wf2T,
           __bf16* __restrict__ Win_b, __bf16* __restrict__ Wo_b,
           float* __restrict__ part)
{
    __shared__ float tile[32][33];
    int id = blockIdx.x;
    int tid = threadIdx.x;
    if (id < 12288) {
        const float* W; __bf16* WT; int K, N, n0, k0;
        if (id < 4096) {
            int m = id >> 10; id &= 1023;
            K = 1024; N = 1024;
            n0 = (id & 31) * 32; k0 = (id >> 5) * 32;
            W = m == 0 ? Wq : (m == 1 ? Wk : (m == 2 ? Wv : W2));
            WT = m == 3 ? W2T : WqkvT + (size_t)m * 1024 * 1024;
        } else if (id < 8192) {
            id -= 4096;
            K = 1024; N = 4096;
            n0 = (id & 127) * 32; k0 = (id >> 7) * 32;
            W = Wf1; WT = Wf1T;
        } else {
            id -= 8192;
            K = 4096; N = 1024;
            n0 = (id & 31) * 32; k0 = (id >> 5) * 32;
            W = Wf2; WT = Wf2T;
        }
        int tx = tid & 31, ty = tid >> 5;
        for (int i = 0; i < 4; i++)
            tile[ty + i * 8][tx] = W[(size_t)(k0 + ty + i * 8) * N + n0 + tx];
        __syncthreads();
        for (int i = 0; i < 4; i++)
            WT[(size_t)(n0 + ty + i * 8) * K + k0 + tx] = (__bf16)tile[tx][ty + i * 8];
        return;
    }
    id -= 12288;
    if (id < 2048) {
        const float* W = id < 1024 ? W_in : Wo;
        __bf16* o = id < 1024 ? Win_b : Wo_b;
        int i = (id & 1023) * 256 + tid;
        float4 v = ((const float4*)W)[i];
        uint2 pk;
        pk.x = pack_bf16x2(v.x, v.y);
        pk.y = pack_bf16x2(v.z, v.w);
        ((uint2*)o)[i] = pk;
        return;
    }
    id -= 2048;
    {
        int n = (id & 15) * 256 + tid;
        int kc = id >> 4;
        int sel = n >> 10, col = n & 1023;
        const float* W = sel == 0 ? Wq : (sel == 1 ? Wk : (sel == 2 ? Wv : W2));
        const float* src = sel < 3 ? b_in : bo;
        float s = 0.f;
        for (int k = kc * 128; k < kc * 128 + 128; k++)
            s += src[k] * W[(size_t)k * 1024 + col];
        part[kc * 4096 + n] = s;
    }
}

// ---------------------------------------------------------------------------
// prep2: [0,384) WqkvCT gemm; [384,512) WcombT gemm; [512,528) bias_stage2;
// [528,2576) LN1 rows.  (GEMM ranges XCD-swizzled.)
// ---------------------------------------------------------------------------
__global__ __launch_bounds__(256, 2)
void prep2(const __bf16* __restrict__ WqkvT, const __bf16* __restrict__ Win_b,
           __bf16* __restrict__ WqkvCT,
           const __bf16* __restrict__ W2T, const __bf16* __restrict__ Wo_b,
           __bf16* __restrict__ WcombT,
           const float* __restrict__ part,
           const float* __restrict__ bq, const float* __restrict__ bk,
           const float* __restrict__ bv, const float* __restrict__ b2,
           float* __restrict__ bqkv, float* __restrict__ bcomb,
           const float* __restrict__ x, const float* __restrict__ g1,
           const float* __restrict__ beta1, __bf16* __restrict__ xn_b)
{
    __shared__ uint4 As[128 * 8];
    __shared__ uint4 Bs[64 * 8];
    int id = blockIdx.x;
    int tid = threadIdx.x;
    if (id < 384) {
        int lg = swz8(id, 384);
        gemm_dev<64, false, false, false, false, true, false>(
            WqkvT, Win_b, nullptr, nullptr, nullptr, nullptr, WqkvCT, nullptr,
            1024, 1024, 1024, lg & 15, lg >> 4, As, Bs);
        return;
    }
    id -= 384;
    if (id < 128) {
        int lg = swz8(id, 128);
        gemm_dev<64, false, false, false, false, true, false>(
            W2T, Wo_b, nullptr, nullptr, nullptr, nullptr, WcombT, nullptr,
            1024, 1024, 1024, lg & 15, lg >> 4, As, Bs);
        return;
    }
    id -= 128;
    if (id < 16) {
        int n = id * 256 + tid;
        int sel = n >> 10, col = n & 1023;
        float s = sel == 0 ? bq[col] : (sel == 1 ? bk[col] : (sel == 2 ? bv[col] : b2[col]));
        for (int kc = 0; kc < 8; kc++) s += part[kc * 4096 + n];
        if (n < 3072) bqkv[n] = s; else bcomb[col] = s;
        return;
    }
    id -= 16;
    ln_row(id, x, g1, beta1, xn_b, nullptr, (float*)As);
}

// ---------------------------------------------------------------------------
// qkv_zf: [0,384) qkv GEMM (swizzled, fused VT epilogue); [384,1344) P zero-fill
// ---------------------------------------------------------------------------
__global__ __launch_bounds__(256, 2)
void qkv_zf(const __bf16* __restrict__ xn_b, const __bf16* __restrict__ WqkvCT,
            const float* __restrict__ bqkv, __bf16* __restrict__ qkv_b,
            __bf16* __restrict__ vt, float* __restrict__ P)
{
    __shared__ uint4 As[128 * 8];
    __shared__ uint4 Bs[128 * 8];
    if (blockIdx.x < 384) {
        int lg = swz8(blockIdx.x, 384);
        gemm_dev<128, false, false, false, false, true, true>(
            xn_b, WqkvCT, bqkv, nullptr, nullptr, nullptr, qkv_b, vt,
            3072, 1024, 1024, lg % 24, lg / 24, As, Bs);
        return;
    }
    zfill_tile(P, blockIdx.x - 384);
}

// ---------------------------------------------------------------------------
// part1_split: split-K x2 of part1 = ctx @ Wcomb (swizzled within halves).
// ---------------------------------------------------------------------------
__global__ __launch_bounds__(256, 2)
void part1_split(const __bf16* __restrict__ ctx_b, const __bf16* __restrict__ WcombT,
                 float* __restrict__ pA, float* __restrict__ pB)
{
    __shared__ uint4 As[128 * 8];
    __shared__ uint4 Bs[64 * 8];
    int half = blockIdx.x >> 8;
    int b2 = swz8(blockIdx.x & 255, 256);
    const __bf16* Ah = ctx_b + half * 512;
    const __bf16* Bh = WcombT + half * 512;
    float* Cf = half ? pB : pA;
    gemm_dev<64, false, false, false, true, false, false>(
        Ah, Bh, nullptr, nullptr, nullptr, Cf, nullptr, nullptr,
        1024, 1024, 512, b2 & 15, b2 >> 4, As, Bs);
}

// ---------------------------------------------------------------------------
// ln2_fused: part1 = pA + pB + x + bcomb[col]; then LayerNorm
// ---------------------------------------------------------------------------
__global__ __launch_bounds__(256)
void ln2_fused(const float* __restrict__ pA, const float* __restrict__ pB,
               const float* __restrict__ x, const float* __restrict__ bcomb,
               const float* __restrict__ gamma, const float* __restrict__ beta,
               __bf16* __restrict__ outb, float* __restrict__ outf)
{
    __shared__ float red[8];
    int row = blockIdx.x;
    int tid = threadIdx.x;
    float4 a = ((const float4*)(pA + (size_t)row * D_MOD))[tid];
    float4 b = ((const float4*)(pB + (size_t)row * D_MOD))[tid];
    float4 xv = ((const float4*)(x + (size_t)row * D_MOD))[tid];
    float4 bc = ((const float4*)bcomb)[tid];
    float4 v;
    v.x = a.x + b.x + xv.x + bc.x;
    v.y = a.y + b.y + xv.y + bc.y;
    v.z = a.z + b.z + xv.z + bc.z;
    v.w = a.w + b.w + xv.w + bc.w;
    ln_row_v(row, v, gamma, beta, outb, outf, red);
}

// ---------------------------------------------------------------------------
// attn_flash v7: dbuf K/V + counted vmcnt + setprio around MFMA clusters.
// Flash blocks [0,512); blocks [512,1472): P zero-fill (zid 960..1919).
// ---------------------------------------------------------------------------
__global__ __launch_bounds__(256, 2)
void attn_flash(const __bf16* __restrict__ qkv, const __bf16* __restrict__ vt,
                float* __restrict__ Obuf, __bf16* __restrict__ ctx,
                float* __restrict__ P)
{
    __shared__ char Ks[2][16384];
    __shared__ char Vs[2][16384];
    __shared__ char Plds[4][4096];
    const int tid = threadIdx.x;

    if (blockIdx.x >= 512) {
        zfill_tile(P, 960 + (int)blockIdx.x - 512);
        return;
    }

    const int lane = tid & 63;
    const int w = tid >> 6;
    const int lrow = lane & 15;
    const int g = lane >> 4;
    const int h = blockIdx.x & 15;
    const int b = 31 - ((int)blockIdx.x >> 4);
    const int qg = b * 64 + w * 16 + lrow;
    const int ntiles = (b >> 1) + 1;
    const float c1 = 0.18033688f;
    const __bf16* ksec = qkv + 1024;
    char* plB = Plds[w];

    bf16x8 qf[2];
    qf[0] = *(const bf16x8*)(qkv + (size_t)qg * 3072 + h * DK + g * 8);
    qf[1] = *(const bf16x8*)(qkv + (size_t)qg * 3072 + h * DK + 32 + g * 8);

    float m2 = -1e30f, l = 0.f;
    f32x4 acc2[4];
    #pragma unroll
    for (int i = 0; i < 4; i++) acc2[i] = (f32x4){0.f, 0.f, 0.f, 0.f};

    const int sKrow = (w << 3) + (lane >> 3);
    const int sKch = lane & 7;
    const int sVrow = (w << 2) + (lane >> 4);
    const int sVch = lane & 15;

    auto stage = [&](int kt, int tb) {
        char* KsW = Ks[tb] + w * 1024;
        char* VsW = Vs[tb] + w * 1024;
        #pragma unroll
        for (int p = 0; p < 4; p++) {
            int row = sKrow + p * 32;
            int ch = sKch ^ (row & 7);
            gload16(ksec + (size_t)(kt * 128 + row) * 3072 + h * DK + ch * 8,
                    KsW + p * 4096 + lane * 16);
        }
        #pragma unroll
        for (int p = 0; p < 4; p++) {
            int row = sVrow + p * 16;
            int ch = sVch ^ (row & 7);
            gload16(vt + (size_t)(h * DK + row) * S_LEN + kt * 128 + ch * 8,
                    VsW + p * 4096 + lane * 16);
        }
    };

    stage(0, 0);

    for (int kt = 0; kt < ntiles; kt++) {
        const int cur = kt & 1;
        if (kt + 1 < ntiles) {
            stage(kt + 1, cur ^ 1);
            asm volatile("s_waitcnt vmcnt(8)" ::: "memory");
        } else {
            asm volatile("s_waitcnt vmcnt(0)" ::: "memory");
        }
        __syncthreads();

        const char* Ksb = Ks[cur];
        const char* Vsb = Vs[cur];

        f32x4 acc[8];
        #pragma unroll
        for (int mf = 0; mf < 8; mf++) acc[mf] = (f32x4){0.f, 0.f, 0.f, 0.f};
        __builtin_amdgcn_s_setprio(1);
        #pragma unroll
        for (int kk = 0; kk < 2; kk++)
            #pragma unroll
            for (int mf = 0; mf < 8; mf++) {
                int row = mf * 16 + lrow;
                bf16x8 kf = *(const bf16x8*)(Ksb + row * 128 + (((kk * 4 + g) ^ (row & 7)) << 4));
                acc[mf] = MFMA16(kf, qf[kk], acc[mf]);
            }
        __builtin_amdgcn_s_setprio(0);

        float s[8][4];
        float tmx = -1e30f;
        const bool lastT = (kt == ntiles - 1);
        #pragma unroll
        for (int mf = 0; mf < 8; mf++) {
            int kvb = kt * 128 + mf * 16 + g * 4;
            #pragma unroll
            for (int r = 0; r < 4; r++) {
                float sv = acc[mf][r] * c1;
                if (lastT) sv = (kvb + r <= qg) ? sv : -1e30f;
                s[mf][r] = sv;
                tmx = fmaxf(tmx, sv);
            }
        }
        if (!__all((int)(tmx <= m2 + 6.f))) {
            float tm = fmaxf(tmx, __shfl_xor(tmx, 16));
            tm = fmaxf(tm, __shfl_xor(tm, 32));
            float nm = fmaxf(m2, tm);
            float sc = exp2f(m2 - nm);
            l *= sc;
            #pragma unroll
            for (int md = 0; md < 4; md++) acc2[md] *= sc;
            m2 = nm;
        }
        float sum = 0.f;
        #pragma unroll
        for (int mf = 0; mf < 8; mf++) {
            float p0 = exp2f(s[mf][0] - m2);
            float p1 = exp2f(s[mf][1] - m2);
            float p2 = exp2f(s[mf][2] - m2);
            float p3 = exp2f(s[mf][3] - m2);
            sum += (p0 + p1) + (p2 + p3);
            uint2 pk;
            pk.x = pack_bf16x2(p0, p1);
            pk.y = pack_bf16x2(p2, p3);
            *(uint2*)(plB + ((lrow * 256 + mf * 32 + g * 8) ^ ((lrow & 7) << 4))) = pk;
        }
        l += sum;

        __builtin_amdgcn_s_setprio(1);
        #pragma unroll
        for (int ks = 0; ks < 4; ks++) {
            bf16x8 pf = *(bf16x8*)(plB + ((lrow * 256 + ks * 64 + g * 16) ^ ((lrow & 7) << 4)));
            #pragma unroll
            for (int md = 0; md < 4; md++) {
                int row = md * 16 + lrow;
                bf16x8 vf = *(const bf16x8*)(Vsb + row * 256 + (((ks * 4 + g) ^ (row & 7)) << 4));
                acc2[md] = MFMA16(vf, pf, acc2[md]);
            }
        }
        __builtin_amdgcn_s_setprio(0);
        __syncthreads();
    }

    l += __shfl_xor(l, 16);
    l += __shfl_xor(l, 32);
    float li = 1.f / l;
    if (lane < 16)
        Obuf[h * S_LEN + qg] = -m2 - log2f(l);
    #pragma unroll
    for (int md = 0; md < 4; md++) {
        uint2 pk;
        pk.x = pack_bf16x2(acc2[md][0] * li, acc2[md][1] * li);
        pk.y = pack_bf16x2(acc2[md][2] * li, acc2[md][3] * li);
        *(uint2*)(ctx + (size_t)qg * D_MOD + h * DK + md * 16 + g * 4) = pk;
    }
}

// ---------------------------------------------------------------------------
// ff1_pwrite: [0,512) ff1 GEMM (swizzled); [512,1600) P tiles heads [0,8)
// ---------------------------------------------------------------------------
__global__ __launch_bounds__(256, 2)
void ff1_pwrite(const __bf16* __restrict__ A, const __bf16* __restrict__ BT,
                const float* __restrict__ bias, __bf16* __restrict__ Cb,
                const __bf16* __restrict__ qkv, const float* __restrict__ Obuf,
                float* __restrict__ P)
{
    __shared__ uint4 As[128 * 8];
    __shared__ uint4 Bs[128 * 8];
    if (blockIdx.x < 512) {
        int lg = swz8(blockIdx.x, 512);
        gemm_dev<128, true, false, false, false, true, false>(
            A, BT, bias, nullptr, nullptr, nullptr, Cb, nullptr,
            D_FF, 1024, 1024, lg & 31, lg >> 5, As, Bs);
        return;
    }
    int idp = blockIdx.x - 512;      // [0,1088)
    int h = idp / 136;
    int tt = idp - h * 136;
    int qt = 0;
    while (tt > qt) { tt -= qt + 1; qt++; }
    pwrite_tile(qkv, Obuf, P, h, qt, tt);
}

// ---------------------------------------------------------------------------
// ff2_pwrite: [0,512) ff2 split-K halves (swizzled); [512,1600) P heads [8,16)
// ---------------------------------------------------------------------------
__global__ __launch_bounds__(256, 2)
void ff2_pwrite(const __bf16* __restrict__ ff1_b, const __bf16* __restrict__ Wf2T,
                float* __restrict__ partA, float* __restrict__ partB,
                const __bf16* __restrict__ qkv, const float* __restrict__ Obuf,
                float* __restrict__ P)
{
    __shared__ uint4 As[128 * 8];
    __shared__ uint4 Bs[64 * 8];
    if (blockIdx.x < 512) {
        int half = blockIdx.x >> 8;
        int b2 = swz8(blockIdx.x & 255, 256);
        const __bf16* Ah = ff1_b + half * 2048;
        const __bf16* Bh = Wf2T + half * 2048;
        float* Cf = half ? partB : partA;
        gemm_dev<64, false, false, false, true, false, false>(
            Ah, Bh, nullptr, nullptr, nullptr, Cf, nullptr, nullptr,
            1024, 4096, 2048, b2 & 15, b2 >> 4, As, Bs);
        return;
    }
    int idp = blockIdx.x - 512;      // [0,1088)
    int h = 8 + idp / 136;
    int tt = idp - (idp / 136) * 136;
    int qt = 0;
    while (tt > qt) { tt -= qt + 1; qt++; }
    pwrite_tile(qkv, Obuf, P, h, qt, tt);
}

// ---------------------------------------------------------------------------
// ff2_reduce: out = partA + partB + norm2 + bf2
// ---------------------------------------------------------------------------
__global__ __launch_bounds__(256)
void ff2_reduce(const float* __restrict__ partA, const float* __restrict__ partB,
                const float* __restrict__ norm2f, const float* __restrict__ bf2,
                float* __restrict__ outp)
{
    int idx = blockIdx.x * 256 + threadIdx.x;
    int col = (idx * 4) & 1023;
    f32x4 a = *(const f32x4*)(partA + (size_t)idx * 4);
    f32x4 b = *(const f32x4*)(partB + (size_t)idx * 4);
    f32x4 n = *(const f32x4*)(norm2f + (size_t)idx * 4);
    f32x4 bb = *(const f32x4*)(bf2 + col);
    f32x4 o = a + b + n + bb;
    *(f32x4*)(outp + (size_t)idx * 4) = o;
}

// ---------------------------------------------------------------------------
extern "C" void kernel_launch(void* const* d_in, const int* in_sizes, int n_in,
                              void* d_out, int out_size, void* d_ws, size_t ws_size,
                              hipStream_t stream)
{
    const float* x     = (const float*)d_in[0];
    const float* g1    = (const float*)d_in[1];
    const float* beta1 = (const float*)d_in[2];
    const float* W_in  = (const float*)d_in[3];
    const float* b_in  = (const float*)d_in[4];
    const float* Wq    = (const float*)d_in[5];
    const float* bq    = (const float*)d_in[6];
    const float* Wk    = (const float*)d_in[7];
    const float* bk    = (const float*)d_in[8];
    const float* Wv    = (const float*)d_in[9];
    const float* bv    = (const float*)d_in[10];
    const float* Wo    = (const float*)d_in[11];
    const float* bo    = (const float*)d_in[12];
    const float* W2    = (const float*)d_in[13];
    const float* b2    = (const float*)d_in[14];
    const float* g2    = (const float*)d_in[15];
    const float* beta2 = (const float*)d_in[16];
    const float* Wf1   = (const float*)d_in[17];
    const float* bf1   = (const float*)d_in[18];
    const float* Wf2   = (const float*)d_in[19];
    const float* bf2   = (const float*)d_in[20];

    float* outp = (float*)d_out;                    // [2048][1024]
    float* Pout = outp + (size_t)S_LEN * D_MOD;     // [16][2048][2048]

    char* p = (char*)d_ws;
    auto alloc = [&](size_t b) -> void* {
        void* r = (void*)p;
        p += (b + 255) & ~(size_t)255;
        return r;
    };
    __bf16* WqkvT    = (__bf16*)alloc((size_t)3072 * 1024 * 2);
    __bf16* W2T      = (__bf16*)alloc((size_t)1024 * 1024 * 2);
    __bf16* Wf1T     = (__bf16*)alloc((size_t)D_FF * D_MOD * 2);
    __bf16* Wf2T     = (__bf16*)alloc((size_t)D_MOD * D_FF * 2);
    __bf16* WqkvCT   = (__bf16*)alloc((size_t)3072 * 1024 * 2);
    __bf16* WcombT   = (__bf16*)alloc((size_t)1024 * 1024 * 2);
    float*  bqkv     = (float*)alloc((size_t)3072 * 4);
    float*  bcomb    = (float*)alloc((size_t)1024 * 4);
    float*  biaspart = (float*)alloc((size_t)8 * 4096 * 4);
    __bf16* xn_b     = (__bf16*)alloc((size_t)S_LEN * D_MOD * 2);
    __bf16* qkv_b    = (__bf16*)alloc((size_t)S_LEN * 3072 * 2);
    __bf16* VT       = (__bf16*)alloc((size_t)N_HEADS * DK * S_LEN * 2);
    __bf16* ctx_b    = (__bf16*)alloc((size_t)S_LEN * D_MOD * 2);
    float*  part1f   = (float*)alloc((size_t)S_LEN * D_MOD * 4);
    float*  p1B      = (float*)alloc((size_t)S_LEN * D_MOD * 4);
    float*  norm2f   = (float*)alloc((size_t)S_LEN * D_MOD * 4);
    __bf16* norm2b   = (__bf16*)alloc((size_t)S_LEN * D_MOD * 2);
    __bf16* ff1_b    = (__bf16*)alloc((size_t)S_LEN * D_FF * 2);
    float*  Obuf     = (float*)alloc((size_t)N_HEADS * S_LEN * 4);
    float*  ffpartB  = (float*)alloc((size_t)S_LEN * D_MOD * 4);
    // aliases (lifetimes disjoint, stream-ordered):
    __bf16* Win_b   = (__bf16*)part1f;   // weight staging before part1_split
    __bf16* Wo_b    = (__bf16*)norm2f;   // weight staging before ln2
    float*  ffpartA = part1f;            // ff2 partial after ln2 consumed part1

    dim3 blk(256);

    prep1<<<dim3(14464), blk, 0, stream>>>(Wq, Wk, Wv, W2, Wf1, Wf2, W_in, Wo,
                                           b_in, bo, WqkvT, W2T, Wf1T, Wf2T,
                                           Win_b, Wo_b, biaspart);

    prep2<<<dim3(2576), blk, 0, stream>>>(WqkvT, Win_b, WqkvCT, W2T, Wo_b, WcombT,
                                          biaspart, bq, bk, bv, b2, bqkv, bcomb,
                                          x, g1, beta1, xn_b);

    // qkv GEMM (+ fused VT transpose) + 960 P zero-fill backfill
    qkv_zf<<<dim3(384 + 960), blk, 0, stream>>>(xn_b, WqkvCT, bqkv, qkv_b, VT, Pout);

    // flash attention (dbuf prefetch + setprio) + remaining 960 zero-fill
    attn_flash<<<dim3(512 + 960), blk, 0, stream>>>(qkv_b, VT, Obuf, ctx_b, Pout);

    // part1 split-K x2 (residual+bias folded into LN2)
    part1_split<<<dim3(512), blk, 0, stream>>>(ctx_b, WcombT, part1f, p1B);

    ln2_fused<<<S_LEN, blk, 0, stream>>>(part1f, p1B, x, bcomb, g2, beta2,
                                         norm2b, norm2f);

    ff1_pwrite<<<dim3(512 + 1088), blk, 0, stream>>>(
        norm2b, Wf1T, bf1, ff1_b, qkv_b, Obuf, Pout);

    ff2_pwrite<<<dim3(512 + 1088), blk, 0, stream>>>(
        ff1_b, Wf2T, ffpartA, ffpartB, qkv_b, Obuf, Pout);

    ff2_reduce<<<dim3(2048), blk, 0, stream>>>(ffpartA, ffpartB, norm2f, bf2, outp);
}